// Round 2
// baseline (1377.508 us; speedup 1.0000x reference)
//
#include <hip/hip_runtime.h>
#include <math.h>

#define HW 36864        // 192*192
#define IMGW 192
#define CCH 192
#define DH 48
#define HIDF 510

typedef unsigned short u16;   // raw bf16 bits

__device__ __forceinline__ float b2f(u16 u) { return __uint_as_float(((unsigned)u) << 16); }
__device__ __forceinline__ u16 f2b(float f) {
    unsigned u = __float_as_uint(f);
    return (u16)((u + 0x7FFFu + ((u >> 16) & 1u)) >> 16);   // RNE
}
__device__ __forceinline__ float4 ld4(const float* p) { return *reinterpret_cast<const float4*>(p); }
__device__ __forceinline__ float4 ld4(const u16* p) {
    ushort4 u = *reinterpret_cast<const ushort4*>(p);
    return make_float4(b2f(u.x), b2f(u.y), b2f(u.z), b2f(u.w));
}
__device__ __forceinline__ void st4(float* p, float a, float b, float c, float d) {
    *reinterpret_cast<float4*>(p) = make_float4(a, b, c, d);
}
__device__ __forceinline__ void st4(u16* p, float a, float b, float c, float d) {
    ushort4 u; u.x = f2b(a); u.y = f2b(b); u.z = f2b(c); u.w = f2b(d);
    *reinterpret_cast<ushort4*>(p) = u;
}

// ---------------- zero small buffer ----------------
__global__ __launch_bounds__(256)
void zero_k(float* __restrict__ p, int n)
{
    int i = blockIdx.x * 256 + threadIdx.x;
    if (i < n) p[i] = 0.f;
}

// ---------------- instance norm stats: one block per channel row ----------------
__global__ __launch_bounds__(256)
void stats_k(const float* __restrict__ x, float* __restrict__ stats)
{
    int row = blockIdx.x;
    const float* p = x + (long)row * HW;
    float s = 0.f, s2 = 0.f;
    for (int i = threadIdx.x; i < HW / 4; i += 256) {
        float4 v = reinterpret_cast<const float4*>(p)[i];
        s  += v.x + v.y + v.z + v.w;
        s2 += v.x * v.x + v.y * v.y + v.z * v.z + v.w * v.w;
    }
    for (int off = 32; off; off >>= 1) { s += __shfl_down(s, off); s2 += __shfl_down(s2, off); }
    __shared__ float ws[4], ws2[4];
    int lane = threadIdx.x & 63, wv = threadIdx.x >> 6;
    if (lane == 0) { ws[wv] = s; ws2[wv] = s2; }
    __syncthreads();
    if (threadIdx.x == 0) {
        float S = 0.f, S2 = 0.f;
        for (int w = 0; w < 4; ++w) { S += ws[w]; S2 += ws2[w]; }
        float mean = S / (float)HW;
        float var  = S2 / (float)HW - mean * mean;
        stats[row * 2 + 0] = mean;
        stats[row * 2 + 1] = rsqrtf(var + 1e-5f);
    }
}

// ---------------- sum-of-squares per q/k plane (folded l2norm), per batch ----------------
__global__ __launch_bounds__(256)
void sumsq_k(const u16* __restrict__ qkv, float* __restrict__ norms)
{
    int r = blockIdx.x;              // 0..383 (q then k channels)
    const u16* p = qkv + (long)r * HW;
    float s2 = 0.f;
    for (int i = threadIdx.x; i < HW / 8; i += 256) {
        uint4 u = reinterpret_cast<const uint4*>(p)[i];
        unsigned vv[4] = {u.x, u.y, u.z, u.w};
        #pragma unroll
        for (int q = 0; q < 4; ++q) {
            float lo = __uint_as_float(vv[q] << 16);
            float hi = __uint_as_float(vv[q] & 0xFFFF0000u);
            s2 += lo * lo + hi * hi;
        }
    }
    for (int off = 32; off; off >>= 1) s2 += __shfl_down(s2, off);
    __shared__ float ws2[4];
    int lane = threadIdx.x & 63, wv = threadIdx.x >> 6;
    if (lane == 0) ws2[wv] = s2;
    __syncthreads();
    if (threadIdx.x == 0) {
        float S2 = 0.f;
        for (int w = 0; w < 4; ++w) S2 += ws2[w];
        norms[r] = sqrtf(S2);
    }
}

// ---------------- tiled f32 GEMM (per batch): C = A * B (+bias, +resid), opt. instnorm on B rows ----
// BM=64, BN=128, BK=16, 256 threads, thread tile 4x8
template<typename TB, typename TC, bool NORM_B, bool RESID>
__global__ __launch_bounds__(256)
void gemm_k(const float* __restrict__ A, int M, int K,
            const TB* __restrict__ B,
            const float* __restrict__ stats,
            const float* __restrict__ bias,
            const float* __restrict__ R,
            TC* __restrict__ C)
{
    __shared__ float At[16][64];
    __shared__ float Bs[16][128];
    const int tid = threadIdx.x;
    const int n0 = blockIdx.x * 128;
    const int m0 = blockIdx.y * 64;

    float acc[4][8];
    #pragma unroll
    for (int i = 0; i < 4; ++i)
        #pragma unroll
        for (int j = 0; j < 8; ++j) acc[i][j] = 0.f;

    const int tm = tid >> 4;
    const int tn = tid & 15;

    const int nk = (K + 15) / 16;
    for (int kc = 0; kc < nk; ++kc) {
        int k0 = kc * 16;
        {   // stage A (guarded scalar)
            int m  = tid >> 2;
            int kb = (tid & 3) * 4;
            int gm = m0 + m;
            #pragma unroll
            for (int j = 0; j < 4; ++j) {
                int gk = k0 + kb + j;
                At[kb + j][m] = (gm < M && gk < K) ? A[(long)gm * K + gk] : 0.f;
            }
        }
        #pragma unroll
        for (int s = tid; s < 512; s += 256) {   // stage B: 512 float4 slots
            int k  = s >> 5;
            int c4 = s & 31;
            int gk = k0 + k;
            float4 v = make_float4(0.f, 0.f, 0.f, 0.f);
            if (gk < K) {
                v = ld4(B + (long)gk * HW + n0 + c4 * 4);
                if (NORM_B) {
                    float mn = stats[gk * 2 + 0];
                    float rs = stats[gk * 2 + 1];
                    v.x = (v.x - mn) * rs; v.y = (v.y - mn) * rs;
                    v.z = (v.z - mn) * rs; v.w = (v.w - mn) * rs;
                }
            }
            *reinterpret_cast<float4*>(&Bs[k][c4 * 4]) = v;
        }
        __syncthreads();
        #pragma unroll
        for (int kk = 0; kk < 16; ++kk) {
            float4 a  = *reinterpret_cast<const float4*>(&At[kk][tm * 4]);
            float4 b0 = *reinterpret_cast<const float4*>(&Bs[kk][tn * 4]);
            float4 b1 = *reinterpret_cast<const float4*>(&Bs[kk][64 + tn * 4]);
            float av[4] = {a.x, a.y, a.z, a.w};
            float bv[8] = {b0.x, b0.y, b0.z, b0.w, b1.x, b1.y, b1.z, b1.w};
            #pragma unroll
            for (int i = 0; i < 4; ++i)
                #pragma unroll
                for (int j = 0; j < 8; ++j)
                    acc[i][j] += av[i] * bv[j];
        }
        __syncthreads();
    }
    #pragma unroll
    for (int i = 0; i < 4; ++i) {
        int gm = m0 + tm * 4 + i;
        if (gm >= M) continue;
        float bs = bias[gm];
        long rowoff = (long)gm * HW + n0;
        float o[8];
        #pragma unroll
        for (int j = 0; j < 8; ++j) o[j] = acc[i][j] + bs;
        int col0 = tn * 4, col1 = 64 + tn * 4;
        if (RESID) {
            float4 r0 = ld4(R + rowoff + col0);
            float4 r1 = ld4(R + rowoff + col1);
            o[0] += r0.x; o[1] += r0.y; o[2] += r0.z; o[3] += r0.w;
            o[4] += r1.x; o[5] += r1.y; o[6] += r1.z; o[7] += r1.w;
        }
        st4(C + rowoff + col0, o[0], o[1], o[2], o[3]);
        st4(C + rowoff + col1, o[4], o[5], o[6], o[7]);
    }
}

// ---------------- depthwise 3x3 (SAME), per batch; plane == channel ----------------
__global__ __launch_bounds__(256)
void dwconv_k(const u16* __restrict__ in, const float* __restrict__ dww,
              const float* __restrict__ dwb, u16* __restrict__ out)
{
    int plane = blockIdx.y;
    int r0 = blockIdx.x * 16;
    const u16* p = in + (long)plane * HW;
    __shared__ float buf[18][IMGW];
    int tid = threadIdx.x;
    for (int i4 = tid; i4 < 18 * 48; i4 += 256) {
        int r = i4 / 48, c4 = (i4 % 48) * 4;
        int gr = r0 - 1 + r;
        float4 v = (gr >= 0 && gr < IMGW) ? ld4(p + (long)gr * IMGW + c4)
                                          : make_float4(0.f, 0.f, 0.f, 0.f);
        *reinterpret_cast<float4*>(&buf[r][c4]) = v;
    }
    float w[9];
    #pragma unroll
    for (int j = 0; j < 9; ++j) w[j] = dww[plane * 9 + j];
    float bias = dwb[plane];
    __syncthreads();
    for (int i4 = tid; i4 < 16 * 48; i4 += 256) {
        int r = i4 / 48, c0 = (i4 % 48) * 4;
        float res[4];
        #pragma unroll
        for (int j = 0; j < 4; ++j) {
            int c = c0 + j;
            float a = bias;
            #pragma unroll
            for (int di = 0; di < 3; ++di)
                #pragma unroll
                for (int dj = 0; dj < 3; ++dj) {
                    int cc = c + dj - 1;
                    if (cc >= 0 && cc < IMGW) a += buf[r + di][cc] * w[di * 3 + dj];
                }
            res[j] = a;
        }
        st4(out + (long)plane * HW + (long)(r0 + r) * IMGW + c0, res[0], res[1], res[2], res[3]);
    }
}

// ---------------- depthwise 3x3 on gate pair + GELU, per batch ----------------
__device__ __forceinline__ float gelu_exact(float x) {
    return 0.5f * x * (1.f + erff(x * 0.70710678118654752f));
}

__global__ __launch_bounds__(256)
void dwconv_gate_k(const u16* __restrict__ t2, const float* __restrict__ dww,
                   const float* __restrict__ dwb, u16* __restrict__ g)
{
    int j = blockIdx.y;                 // 0..509
    int r0 = blockIdx.x * 16;
    const u16* p1 = t2 + (long)j * HW;
    const u16* p2 = t2 + (long)(HIDF + j) * HW;
    __shared__ float buf1[18][IMGW];
    __shared__ float buf2[18][IMGW];
    int tid = threadIdx.x;
    for (int i4 = tid; i4 < 18 * 48; i4 += 256) {
        int r = i4 / 48, c4 = (i4 % 48) * 4;
        int gr = r0 - 1 + r;
        bool ok = (gr >= 0 && gr < IMGW);
        float4 v1 = ok ? ld4(p1 + (long)gr * IMGW + c4) : make_float4(0.f, 0.f, 0.f, 0.f);
        float4 v2 = ok ? ld4(p2 + (long)gr * IMGW + c4) : make_float4(0.f, 0.f, 0.f, 0.f);
        *reinterpret_cast<float4*>(&buf1[r][c4]) = v1;
        *reinterpret_cast<float4*>(&buf2[r][c4]) = v2;
    }
    float w1[9], w2[9];
    #pragma unroll
    for (int q = 0; q < 9; ++q) { w1[q] = dww[j * 9 + q]; w2[q] = dww[(HIDF + j) * 9 + q]; }
    float b1 = dwb[j], b2 = dwb[HIDF + j];
    __syncthreads();
    for (int i4 = tid; i4 < 16 * 48; i4 += 256) {
        int r = i4 / 48, c0 = (i4 % 48) * 4;
        float res[4];
        #pragma unroll
        for (int jj = 0; jj < 4; ++jj) {
            int c = c0 + jj;
            float a1 = b1, a2 = b2;
            #pragma unroll
            for (int di = 0; di < 3; ++di)
                #pragma unroll
                for (int dj = 0; dj < 3; ++dj) {
                    int cc = c + dj - 1;
                    if (cc >= 0 && cc < IMGW) {
                        a1 += buf1[r + di][cc] * w1[di * 3 + dj];
                        a2 += buf2[r + di][cc] * w2[di * 3 + dj];
                    }
                }
            res[jj] = gelu_exact(a1) * a2;
        }
        st4(g + (long)j * HW + (long)(r0 + r) * IMGW + c0, res[0], res[1], res[2], res[3]);
    }
}

// ---------------- raw attention scores (split-K atomics), per batch ----------------
__global__ __launch_bounds__(256)
void attn_k(const u16* __restrict__ qkv, float* __restrict__ attn_raw)
{
    __shared__ float qs[48][68];
    __shared__ float ks[48][68];
    int h = blockIdx.y;
    int n0 = blockIdx.x * 256;
    const u16* qbase = qkv + (long)(h * DH) * HW;
    const u16* kbase = qkv + (long)(CCH + h * DH) * HW;
    int tid = threadIdx.x;
    int cg = tid >> 4, dg = tid & 15;
    float acc[3][3] = {{0.f}};
    for (int sub = 0; sub < 4; ++sub) {
        int nb = n0 + sub * 64;
        for (int s = tid; s < 768; s += 256) {
            int ch = s >> 4, c4 = s & 15;
            float4 qv = ld4(qbase + (long)ch * HW + nb + c4 * 4);
            float4 kv = ld4(kbase + (long)ch * HW + nb + c4 * 4);
            *reinterpret_cast<float4*>(&qs[ch][c4 * 4]) = qv;
            *reinterpret_cast<float4*>(&ks[ch][c4 * 4]) = kv;
        }
        __syncthreads();
        for (int kk = 0; kk < 64; kk += 4) {
            float4 qv[3], kv[3];
            #pragma unroll
            for (int i = 0; i < 3; ++i) qv[i] = *reinterpret_cast<const float4*>(&qs[cg * 3 + i][kk]);
            #pragma unroll
            for (int j = 0; j < 3; ++j) kv[j] = *reinterpret_cast<const float4*>(&ks[dg * 3 + j][kk]);
            #pragma unroll
            for (int i = 0; i < 3; ++i)
                #pragma unroll
                for (int j = 0; j < 3; ++j)
                    acc[i][j] += qv[i].x * kv[j].x + qv[i].y * kv[j].y
                               + qv[i].z * kv[j].z + qv[i].w * kv[j].w;
        }
        __syncthreads();
    }
    float* araw = attn_raw + (long)h * DH * DH;
    #pragma unroll
    for (int i = 0; i < 3; ++i)
        #pragma unroll
        for (int j = 0; j < 3; ++j)
            atomicAdd(&araw[(cg * 3 + i) * DH + dg * 3 + j], acc[i][j]);
}

// ---------------- softmax + fold attn into attn_out_w: W2[o, h*48+d], per batch ----------------
__global__ __launch_bounds__(256)
void softmax_w2_k(const float* __restrict__ attn_raw, const float* __restrict__ norms,
                  const float* __restrict__ temp, const float* __restrict__ aow,
                  float* __restrict__ W2)
{
    int h = blockIdx.x;
    __shared__ float sm[48][48];
    const float* araw = attn_raw + (long)h * DH * DH;
    const float* nq = norms + h * DH;
    const float* nk = norms + CCH + h * DH;
    float t = temp[h];
    int tid = threadIdx.x;
    if (tid < DH) {
        int c = tid;
        float qn = fmaxf(nq[c], 1e-12f);
        float row[DH];
        float mx = -1e30f;
        for (int d = 0; d < DH; ++d) {
            float kn = fmaxf(nk[d], 1e-12f);
            float v = araw[c * DH + d] * t / (qn * kn);
            row[d] = v; mx = fmaxf(mx, v);
        }
        float ssum = 0.f;
        for (int d = 0; d < DH; ++d) { float e = expf(row[d] - mx); row[d] = e; ssum += e; }
        float inv = 1.f / ssum;
        for (int d = 0; d < DH; ++d) sm[c][d] = row[d] * inv;
    }
    __syncthreads();
    for (int i = tid; i < CCH * DH; i += 256) {
        int o = i / DH, d = i % DH;
        float s = 0.f;
        const float* ar = aow + (long)o * CCH + h * DH;
        for (int c = 0; c < DH; ++c) s += ar[c] * sm[c][d];
        W2[(long)o * CCH + h * DH + d] = s;
    }
}

extern "C" void kernel_launch(void* const* d_in, const int* in_sizes, int n_in,
                              void* d_out, int out_size, void* d_ws, size_t ws_size,
                              hipStream_t stream) {
    const float* x           = (const float*)d_in[0];
    const float* qkv_w       = (const float*)d_in[1];
    const float* qkv_bias    = (const float*)d_in[2];
    const float* qkv_dw_w    = (const float*)d_in[3];
    const float* qkv_dw_b    = (const float*)d_in[4];
    const float* attn_out_w  = (const float*)d_in[5];
    const float* attn_out_b  = (const float*)d_in[6];
    const float* temperature = (const float*)d_in[7];
    const float* proj_in_w   = (const float*)d_in[8];
    const float* proj_in_b   = (const float*)d_in[9];
    const float* dw_w        = (const float*)d_in[10];
    const float* dw_b        = (const float*)d_in[11];
    const float* proj_out_w  = (const float*)d_in[12];
    const float* proj_out_b  = (const float*)d_in[13];
    float* out = (float*)d_out;
    char* ws8 = (char*)d_ws;

    // Per-batch bf16 intermediates; total ws usage ~108 MB.
    u16* t1   = (u16*)(ws8);                          // [576,HW]  42.5 MB
    u16* qkvb = (u16*)(ws8 + (long)576 * HW * 2);     // [576,HW]  42.5 MB (ends 85 MB)
    u16* t2   = (u16*)(ws8);                          // [1020,HW] 75.2 MB (reuses t1+qkvb)
    u16* g    = (u16*)(ws8 + (long)1020 * HW * 2);    // [510,HW]  37.6 MB (ends 112.8 MB)
    char* smalls = ws8 + (long)1530 * HW * 2;
    float* stats1   = (float*)(smalls);               // 192*2
    float* stats2   = stats1 + 384;
    float* norms    = stats2 + 384;                   // 384
    float* attn_raw = norms + 384;                    // 4*48*48
    float* W2       = attn_raw + 4 * DH * DH;         // 192*192

    for (int b = 0; b < 2; ++b) {
        const float* xb = x + (long)b * CCH * HW;
        float* outb = out + (long)b * CCH * HW;

        // ---- attention branch ----
        stats_k<<<192, 256, 0, stream>>>(xb, stats1);
        gemm_k<float, u16, true, false><<<dim3(288, 9), 256, 0, stream>>>(
            qkv_w, 576, 192, xb, stats1, qkv_bias, nullptr, t1);
        dwconv_k<<<dim3(12, 576), 256, 0, stream>>>(t1, qkv_dw_w, qkv_dw_b, qkvb);
        sumsq_k<<<384, 256, 0, stream>>>(qkvb, norms);
        zero_k<<<36, 256, 0, stream>>>(attn_raw, 4 * DH * DH);
        attn_k<<<dim3(144, 4), 256, 0, stream>>>(qkvb, attn_raw);
        softmax_w2_k<<<4, 256, 0, stream>>>(attn_raw, norms, temperature, attn_out_w, W2);
        gemm_k<u16, float, false, true><<<dim3(288, 3), 256, 0, stream>>>(
            W2, 192, 192, qkvb + (long)384 * HW, nullptr, attn_out_b, xb, outb);

        // ---- GDFN branch ----
        stats_k<<<192, 256, 0, stream>>>(outb, stats2);
        gemm_k<float, u16, true, false><<<dim3(288, 16), 256, 0, stream>>>(
            proj_in_w, 1020, 192, outb, stats2, proj_in_b, nullptr, t2);
        dwconv_gate_k<<<dim3(12, 510), 256, 0, stream>>>(t2, dw_w, dw_b, g);
        gemm_k<u16, float, false, true><<<dim3(288, 3), 256, 0, stream>>>(
            proj_out_w, 192, 510, g, nullptr, proj_out_b, outb, outb);
    }
}

// Round 3
// 976.533 us; speedup vs baseline: 1.4106x; 1.4106x over previous
//
#include <hip/hip_runtime.h>
#include <math.h>

#define HW 36864
#define IMGW 192

typedef unsigned short u16;
typedef __attribute__((ext_vector_type(8))) short short8;
typedef __attribute__((ext_vector_type(8))) unsigned short ushort8;
typedef __attribute__((ext_vector_type(16))) float f32x16;

__device__ __forceinline__ float b2f(u16 u){ return __uint_as_float(((unsigned)u)<<16); }
__device__ __forceinline__ u16 f2b(float f){
    unsigned u = __float_as_uint(f);
    return (u16)((u + 0x7FFFu + ((u>>16)&1u)) >> 16);   // RNE
}
__device__ __forceinline__ int perm1020(int m){ return (m&1) ? 510+(m>>1) : (m>>1); }
__device__ __forceinline__ float gelu_exact(float x){
    return 0.5f * x * (1.f + erff(x * 0.70710678118654752f));
}

// ---------------- zero small buffer ----------------
__global__ __launch_bounds__(256)
void zero_k(float* __restrict__ p, int n)
{
    int i = blockIdx.x * 256 + threadIdx.x;
    if (i < n) p[i] = 0.f;
}

// ---------------- instance norm stats over f32 [row][HW]: (mean, rsqrt, sigma, 0) ----------------
__global__ __launch_bounds__(256)
void stats_k(const float* __restrict__ x, float4* __restrict__ stats)
{
    int row = blockIdx.x;
    const float* p = x + (long)row * HW;
    float s = 0.f, s2 = 0.f;
    for (int i = threadIdx.x; i < HW/4; i += 256) {
        float4 v = reinterpret_cast<const float4*>(p)[i];
        s  += v.x + v.y + v.z + v.w;
        s2 += v.x*v.x + v.y*v.y + v.z*v.z + v.w*v.w;
    }
    for (int off = 32; off; off >>= 1) { s += __shfl_down(s, off); s2 += __shfl_down(s2, off); }
    __shared__ float ws[4], ws2[4];
    int lane = threadIdx.x & 63, wv = threadIdx.x >> 6;
    if (lane == 0) { ws[wv] = s; ws2[wv] = s2; }
    __syncthreads();
    if (threadIdx.x == 0) {
        float S = 0.f, S2 = 0.f;
        for (int w = 0; w < 4; ++w) { S += ws[w]; S2 += ws2[w]; }
        float mean = S / (float)HW;
        float var  = S2 / (float)HW - mean*mean;
        float rs = rsqrtf(var + 1e-5f);
        float sg = sqrtf(var + 1e-5f);
        stats[row] = make_float4(mean, rs, sg, 0.f);
    }
}

// ---------------- transpose+normalize: x[c][n] f32 -> xn[n][c] bf16 (per batch) ----------------
__global__ __launch_bounds__(256)
void tn_k(const float* __restrict__ xb, const float4* __restrict__ st, u16* __restrict__ xn)
{
    __shared__ float L[64 * 196];
    long n0 = (long)blockIdx.x * 64;
    int tid = threadIdx.x;
    #pragma unroll
    for (int i = 0; i < 48; ++i) {
        int idx = tid + i*256;          // 12288 = 64n x 192c
        int n = idx & 63, c = idx >> 6;
        L[n*196 + c] = xb[(long)c*HW + n0 + n];
    }
    __syncthreads();
    #pragma unroll
    for (int i = 0; i < 6; ++i) {
        int idx = tid + i*256;          // 1536 = 64n x 24oct
        int oc = idx % 24, n = idx / 24;
        ushort8 v;
        #pragma unroll
        for (int e = 0; e < 8; ++e) {
            int c = oc*8 + e;
            float4 s = st[c];
            v[e] = f2b((L[n*196 + c] - s.x) * s.y);
        }
        *reinterpret_cast<ushort8*>(xn + (n0+n)*192 + oc*8) = v;
    }
}

// ---------------- MFMA GEMM: out[n][m] = sum_k B[n][k] * W[m][k], channel-last ----------------
// block: 128 n-rows x BM m-cols, 4 waves (2n x 2m), 32x32x16 bf16 MFMA, BK=64
template<int BM, bool PERM, bool KTAIL, bool NORMB, int RESID, bool OUTT>
__global__ __launch_bounds__(256)
void gemm_k(const float* __restrict__ A, int mbase, int Ksrc, int K64,
            const u16* __restrict__ B, int brs,
            const float* __restrict__ bias,
            const u16* __restrict__ Rs,
            const float4* __restrict__ st1,
            const float* __restrict__ s2m, const float* __restrict__ s2r,
            u16* __restrict__ outA, int ors,
            float* __restrict__ outT)
{
    constexpr int MR  = BM / 64;
    constexpr int OLS = BM + 8;
    constexpr int LDS_MAIN = 8192 + BM*64;
    constexpr int LDS_OUT  = 128*OLS;
    constexpr int LDSU = LDS_MAIN > LDS_OUT ? LDS_MAIN : LDS_OUT;
    __shared__ u16 lds[LDSU];
    u16* Xl = lds;              // [128][64] swizzled
    u16* Wl = lds + 8192;       // [BM][64] swizzled

    const int tid = threadIdx.x;
    const int m0 = blockIdx.x * BM;
    const long nn0 = (long)blockIdx.y * 128;
    const int ln = tid & 63, wv = tid >> 6;
    const int wn = (wv >> 1) * 64;
    const int wm = (wv & 1) * (BM/2);
    const int l31 = ln & 31, l5 = ln >> 5;

    f32x16 acc[2][MR];
    #pragma unroll
    for (int a = 0; a < 2; ++a)
        #pragma unroll
        for (int b = 0; b < MR; ++b)
            #pragma unroll
            for (int r = 0; r < 16; ++r) acc[a][b][r] = 0.f;

    for (int ks = 0; ks < K64; ++ks) {
        if (ks) __syncthreads();
        // ---- stage X: 128 rows x 64 k (bf16 from global, swizzled slots) ----
        #pragma unroll
        for (int i = 0; i < 4; ++i) {
            int task = tid + i*256;           // 1024
            int row = task >> 3, o = task & 7;
            ushort8 v = *reinterpret_cast<const ushort8*>(B + (nn0+row)*(long)brs + ks*64 + o*8);
            if (NORMB) {
                int kb = ks*64 + o*8;
                #pragma unroll
                for (int e = 0; e < 8; ++e) {
                    float mn = s2m[kb+e], rr = s2r[kb+e];
                    v[e] = f2b((b2f(v[e]) - mn) * rr);
                }
            }
            int slot = o ^ ((row >> 1) & 7);
            *reinterpret_cast<ushort8*>(&Xl[row*64 + slot*8]) = v;
        }
        // ---- stage W: BM rows x 64 k (f32 -> bf16, swizzled) ----
        #pragma unroll
        for (int i = 0; i < BM/32; ++i) {
            int task = tid + i*256;           // BM*8
            int rowm = task >> 3, o = task & 7;
            int gm = mbase + m0 + rowm;
            bool valid = !PERM || (gm < 1020);
            int srow = PERM ? (valid ? perm1020(gm) : 0) : gm;
            ushort8 w8;
            #pragma unroll
            for (int e = 0; e < 8; ++e) {
                int k = ks*64 + o*8 + e;
                float f = 0.f;
                if (valid && (!KTAIL || k < Ksrc)) f = A[(long)srow*Ksrc + k];
                w8[e] = f2b(f);
            }
            int slot = o ^ ((rowm >> 1) & 7);
            *reinterpret_cast<ushort8*>(&Wl[rowm*64 + slot*8]) = w8;
        }
        __syncthreads();
        // ---- MFMA ----
        #pragma unroll
        for (int k16 = 0; k16 < 4; ++k16) {
            short8 af[2];
            #pragma unroll
            for (int nr = 0; nr < 2; ++nr) {
                int row = wn + nr*32 + l31;
                int slot = (k16*2 + l5) ^ ((row >> 1) & 7);
                af[nr] = *reinterpret_cast<const short8*>(&Xl[row*64 + slot*8]);
            }
            short8 bf[MR];
            #pragma unroll
            for (int mr = 0; mr < MR; ++mr) {
                int rowm = wm + mr*32 + l31;
                int slot = (k16*2 + l5) ^ ((rowm >> 1) & 7);
                bf[mr] = *reinterpret_cast<const short8*>(&Wl[rowm*64 + slot*8]);
            }
            #pragma unroll
            for (int nr = 0; nr < 2; ++nr)
                #pragma unroll
                for (int mr = 0; mr < MR; ++mr)
                    acc[nr][mr] = __builtin_amdgcn_mfma_f32_32x32x16_bf16(af[nr], bf[mr], acc[nr][mr], 0, 0, 0);
        }
    }
    // ---- epilogue: bias (+stage-resid), transpose-stage to LDS ----
    float bsv[MR];
    #pragma unroll
    for (int mr = 0; mr < MR; ++mr) {
        int gm = mbase + m0 + wm + mr*32 + l31;
        if (PERM) bsv[mr] = (gm < 1020) ? bias[perm1020(gm)] : 0.f;
        else      bsv[mr] = bias[gm];
    }
    __syncthreads();
    u16* Ol = lds;
    #pragma unroll
    for (int nr = 0; nr < 2; ++nr)
        #pragma unroll
        for (int mr = 0; mr < MR; ++mr)
            #pragma unroll
            for (int reg = 0; reg < 16; ++reg) {
                int r32 = (reg & 3) + 8*(reg >> 2) + 4*l5;
                int grow = wn + nr*32 + r32;
                int gcol = wm + mr*32 + l31;
                float val = acc[nr][mr][reg] + bsv[mr];
                if (RESID == 2)
                    val += b2f(Rs[(nn0 + grow)*192 + m0 + gcol]);
                Ol[grow*OLS + gcol] = f2b(val);
            }
    __syncthreads();
    if (!OUTT) {
        constexpr int SPR = BM/8;     // 16B chunks per row
        #pragma unroll
        for (int i = 0; i < 128*SPR/256; ++i) {
            int idx = tid + i*256;
            int row = idx / SPR, sl = idx % SPR;
            ushort8 v = *reinterpret_cast<const ushort8*>(&Ol[row*OLS + sl*8]);
            if (RESID == 1) {
                ushort8 rv = *reinterpret_cast<const ushort8*>(Rs + (nn0+row)*192 + m0 + sl*8);
                #pragma unroll
                for (int e = 0; e < 8; ++e) {
                    float4 s = st1[m0 + sl*8 + e];
                    float xr = b2f(rv[e]) * s.z + s.x;     // un-normalize residual
                    v[e] = f2b(b2f(v[e]) + xr);
                }
            }
            *reinterpret_cast<ushort8*>(outA + (nn0+row)*(long)ors + m0 + sl*8) = v;
        }
    } else {
        // transposed f32 output: d_out[m][n]
        int m = tid >> 2, ng = tid & 3;
        float* orow = outT + (long)(m0 + m)*HW + nn0 + ng*32;
        #pragma unroll
        for (int i = 0; i < 32; i += 4) {
            float4 o;
            o.x = b2f(Ol[(ng*32+i+0)*OLS + m]);
            o.y = b2f(Ol[(ng*32+i+1)*OLS + m]);
            o.z = b2f(Ol[(ng*32+i+2)*OLS + m]);
            o.w = b2f(Ol[(ng*32+i+3)*OLS + m]);
            *reinterpret_cast<float4*>(orow + i) = o;
        }
    }
}

// ---------------- depthwise 3x3, channel-last [n][576] (per batch) ----------------
__global__ __launch_bounds__(256)
void dwconv_k(const u16* __restrict__ in, const float* __restrict__ dww,
              const float* __restrict__ dwb, u16* __restrict__ out)
{
    __shared__ float wl[64][9];
    __shared__ float bl[64];
    int cg = blockIdx.y;
    int tid = threadIdx.x;
    for (int i = tid; i < 576; i += 256) { int ch = i/9, j = i%9; wl[ch][j] = dww[(cg*64+ch)*9 + j]; }
    if (tid < 64) bl[tid] = dwb[cg*64 + tid];
    __syncthreads();
    int pix = blockIdx.x*32 + (tid >> 3);
    int x = pix % IMGW, y = pix / IMGW;
    int cl = (tid & 7) * 8;
    int cb = cg*64 + cl;
    float a[8];
    #pragma unroll
    for (int e = 0; e < 8; ++e) a[e] = bl[cl+e];
    #pragma unroll
    for (int dy = -1; dy <= 1; ++dy) {
        int yy = y + dy;
        if (yy < 0 || yy >= IMGW) continue;
        #pragma unroll
        for (int dx = -1; dx <= 1; ++dx) {
            int xx = x + dx;
            if (xx < 0 || xx >= IMGW) continue;
            ushort8 v = *reinterpret_cast<const ushort8*>(in + (long)(yy*IMGW + xx)*576 + cb);
            int j = (dy+1)*3 + (dx+1);
            #pragma unroll
            for (int e = 0; e < 8; ++e) a[e] = fmaf(b2f(v[e]), wl[cl+e][j], a[e]);
        }
    }
    ushort8 o;
    #pragma unroll
    for (int e = 0; e < 8; ++e) o[e] = f2b(a[e]);
    *reinterpret_cast<ushort8*>(out + (long)pix*576 + cb) = o;
}

// ---------------- q/k sum-of-squares per channel (cols 0..383) ----------------
__global__ __launch_bounds__(384)
void nacc_k(const u16* __restrict__ qkvd, float* __restrict__ nacc)
{
    int c = threadIdx.x;
    long r0 = (long)blockIdx.x * 256;
    float s = 0.f;
    for (int i = 0; i < 256; ++i) {
        float f = b2f(qkvd[(r0+i)*576 + c]);
        s += f*f;
    }
    atomicAdd(&nacc[c], s);
}

// ---------------- raw attention scores per head (atomics over n-chunks) ----------------
__global__ __launch_bounds__(256)
void attnscore_k(const u16* __restrict__ qkvd, float* __restrict__ araw)
{
    __shared__ u16 T[96 * 264];
    int h = blockIdx.y;
    long nn0 = (long)blockIdx.x * 256;
    int tid = threadIdx.x;
    #pragma unroll
    for (int i = 0; i < 12; ++i) {
        int task = tid + i*256;            // 3072 = 256n x 12oct
        int oc = task % 12, n = task / 12;
        int cg = (oc < 6) ? (h*48 + oc*8) : (192 + h*48 + (oc-6)*8);
        ushort8 v = *reinterpret_cast<const ushort8*>(qkvd + (nn0+n)*576 + cg);
        int crow = oc*8;
        #pragma unroll
        for (int e = 0; e < 8; ++e) T[(crow+e)*264 + n] = v[e];
    }
    __syncthreads();
    int cg = tid >> 4, dg = tid & 15;
    float acc[3][3] = {{0.f,0.f,0.f},{0.f,0.f,0.f},{0.f,0.f,0.f}};
    for (int o = 0; o < 32; ++o) {
        float qf[3][8], kf[3][8];
        #pragma unroll
        for (int i = 0; i < 3; ++i) {
            short8 q = *reinterpret_cast<const short8*>(&T[(cg*3+i)*264 + o*8]);
            short8 k = *reinterpret_cast<const short8*>(&T[(48 + dg*3+i)*264 + o*8]);
            #pragma unroll
            for (int e = 0; e < 8; ++e) { qf[i][e] = b2f((u16)q[e]); kf[i][e] = b2f((u16)k[e]); }
        }
        #pragma unroll
        for (int i = 0; i < 3; ++i)
            #pragma unroll
            for (int j = 0; j < 3; ++j)
                #pragma unroll
                for (int e = 0; e < 8; ++e)
                    acc[i][j] = fmaf(qf[i][e], kf[j][e], acc[i][j]);
    }
    float* ar = araw + h*2304;
    #pragma unroll
    for (int i = 0; i < 3; ++i)
        #pragma unroll
        for (int j = 0; j < 3; ++j)
            atomicAdd(&ar[(cg*3+i)*48 + dg*3+j], acc[i][j]);
}

// ---------------- softmax + fold into attn_out_w -> W2 ----------------
__global__ __launch_bounds__(256)
void softmax_w2_k(const float* __restrict__ araw, const float* __restrict__ nacc,
                  const float* __restrict__ temp, const float* __restrict__ aow,
                  float* __restrict__ W2)
{
    int h = blockIdx.x;
    __shared__ float sm[48][48];
    const float* ar = araw + h*2304;
    float t = temp[h];
    int tid = threadIdx.x;
    if (tid < 48) {
        int c = tid;
        float qn = fmaxf(sqrtf(nacc[h*48 + c]), 1e-12f);
        float row[48];
        float mx = -1e30f;
        for (int d = 0; d < 48; ++d) {
            float kn = fmaxf(sqrtf(nacc[192 + h*48 + d]), 1e-12f);
            float v = ar[c*48 + d] * t / (qn * kn);
            row[d] = v; mx = fmaxf(mx, v);
        }
        float ssum = 0.f;
        for (int d = 0; d < 48; ++d) { float e = expf(row[d] - mx); row[d] = e; ssum += e; }
        float inv = 1.f / ssum;
        for (int d = 0; d < 48; ++d) sm[c][d] = row[d] * inv;
    }
    __syncthreads();
    for (int i = tid; i < 192*48; i += 256) {
        int o = i / 48, d = i % 48;
        float s = 0.f;
        const float* arow = aow + (long)o*192 + h*48;
        for (int c = 0; c < 48; ++c) s += arow[c] * sm[c][d];
        W2[(long)o*192 + h*48 + d] = s;
    }
}

// ---------------- column stats over x2 [36864][192] bf16 ----------------
__global__ __launch_bounds__(192)
void stat2_k(const u16* __restrict__ x2, float* __restrict__ ss, float* __restrict__ sq)
{
    int c = threadIdx.x;
    long r0 = (long)blockIdx.x * 128;
    float s = 0.f, q = 0.f;
    for (int i = 0; i < 128; ++i) {
        float f = b2f(x2[(r0+i)*192 + c]);
        s += f; q += f*f;
    }
    atomicAdd(&ss[c], s);
    atomicAdd(&sq[c], q);
}

__global__ __launch_bounds__(192)
void fin2_k(const float* __restrict__ ss, const float* __restrict__ sq,
            float* __restrict__ m, float* __restrict__ r)
{
    int c = threadIdx.x;
    float mean = ss[c] / (float)HW;
    float var  = sq[c] / (float)HW - mean*mean;
    m[c] = mean;
    r[c] = rsqrtf(var + 1e-5f);
}

// ---------------- depthwise 3x3 on interleaved pairs + GELU gate (per batch, half) ----------------
__global__ __launch_bounds__(256)
void gate_k(const u16* __restrict__ t2h, const float* __restrict__ dww,
            const float* __restrict__ dwb, u16* __restrict__ g, int jbase)
{
    __shared__ float w1l[64][9], w2l[64][9];
    __shared__ float b1l[64], b2l[64];
    int tid = threadIdx.x;
    int jg = blockIdx.y;     // 0..3 -> 64 j each
    for (int i = tid; i < 1152; i += 256) {
        int half = i >= 576;
        int ii = i - half*576;
        int jj = ii / 9, tap = ii % 9;
        int gj = jbase + jg*64 + jj;
        float w = (gj < 510) ? dww[(long)(half ? 510 + gj : gj)*9 + tap] : 0.f;
        if (half) w2l[jj][tap] = w; else w1l[jj][tap] = w;
    }
    if (tid < 64) {
        int gj = jbase + jg*64 + tid;
        b1l[tid] = (gj < 510) ? dwb[gj] : 0.f;
        b2l[tid] = (gj < 510) ? dwb[510 + gj] : 0.f;
    }
    __syncthreads();
    int pix = blockIdx.x*32 + (tid >> 3);
    int x = pix % IMGW, y = pix / IMGW;
    int jl = (tid & 7) * 8;
    float a1[8], a2[8];
    #pragma unroll
    for (int e = 0; e < 8; ++e) { a1[e] = b1l[jl+e]; a2[e] = b2l[jl+e]; }
    #pragma unroll
    for (int dy = -1; dy <= 1; ++dy) {
        int yy = y + dy;
        if (yy < 0 || yy >= IMGW) continue;
        #pragma unroll
        for (int dx = -1; dx <= 1; ++dx) {
            int xx = x + dx;
            if (xx < 0 || xx >= IMGW) continue;
            const u16* p = t2h + (long)(yy*IMGW + xx)*512 + (jg*64 + jl)*2;
            ushort8 v0 = *reinterpret_cast<const ushort8*>(p);
            ushort8 v1 = *reinterpret_cast<const ushort8*>(p + 8);
            int tap = (dy+1)*3 + (dx+1);
            #pragma unroll
            for (int e = 0; e < 4; ++e) {
                a1[e]   = fmaf(b2f(v0[2*e]),   w1l[jl+e][tap],   a1[e]);
                a2[e]   = fmaf(b2f(v0[2*e+1]), w2l[jl+e][tap],   a2[e]);
                a1[e+4] = fmaf(b2f(v1[2*e]),   w1l[jl+e+4][tap], a1[e+4]);
                a2[e+4] = fmaf(b2f(v1[2*e+1]), w2l[jl+e+4][tap], a2[e+4]);
            }
        }
    }
    ushort8 o;
    #pragma unroll
    for (int e = 0; e < 8; ++e) {
        int gj = jbase + jg*64 + jl + e;
        float val = (gj < 510) ? gelu_exact(a1[e]) * a2[e] : 0.f;
        o[e] = f2b(val);
    }
    *reinterpret_cast<ushort8*>(g + (long)pix*512 + jbase + jg*64 + jl) = o;
}

extern "C" void kernel_launch(void* const* d_in, const int* in_sizes, int n_in,
                              void* d_out, int out_size, void* d_ws, size_t ws_size,
                              hipStream_t stream) {
    const float* x           = (const float*)d_in[0];
    const float* qkv_w       = (const float*)d_in[1];
    const float* qkv_bias    = (const float*)d_in[2];
    const float* qkv_dw_w    = (const float*)d_in[3];
    const float* qkv_dw_b    = (const float*)d_in[4];
    const float* attn_out_w  = (const float*)d_in[5];
    const float* attn_out_b  = (const float*)d_in[6];
    const float* temperature = (const float*)d_in[7];
    const float* proj_in_w   = (const float*)d_in[8];
    const float* proj_in_b   = (const float*)d_in[9];
    const float* dw_w        = (const float*)d_in[10];
    const float* dw_b        = (const float*)d_in[11];
    const float* proj_out_w  = (const float*)d_in[12];
    const float* proj_out_b  = (const float*)d_in[13];
    float* out = (float*)d_out;
    char* ws = (char*)d_ws;

    // slots (per-batch reuse): A = xn -> x2 (in place); C = t1 -> g; D = qkvd -> t2half
    u16* A_ = (u16*)ws;                                   // 36864*192*2 = 14,155,776
    u16* C_ = (u16*)(ws + 14155776);                      // 36864*576*2 = 42,467,328
    u16* D_ = (u16*)(ws + 14155776 + 42467328);           // 42,467,328
    float* S_ = (float*)(ws + 99090432);
    float* nacc = S_;               // 384
    float* s2s  = S_ + 384;         // 192
    float* s2q  = S_ + 576;         // 192
    float* araw = S_ + 768;         // 9216
    float* s2m  = S_ + 9984;        // 192
    float* s2r  = S_ + 10176;       // 192
    float* W2   = S_ + 10368;       // 36864
    float4* st1 = (float4*)(S_ + 47232);  // 384 float4

    stats_k<<<384, 256, 0, stream>>>(x, st1);

    for (int b = 0; b < 2; ++b) {
        const float* xb = x + (long)b * 192 * HW;
        float* outb = out + (long)b * 192 * HW;
        const float4* st1b = st1 + b * 192;

        zero_k<<<39, 256, 0, stream>>>(S_, 9984);
        tn_k<<<576, 256, 0, stream>>>(xb, st1b, A_);

        // G1: t1[n][576] = xn @ qkv_w^T + qkv_b
        gemm_k<64,false,false,false,0,false><<<dim3(9,288), 256, 0, stream>>>(
            qkv_w, 0, 192, 3, A_, 192, qkv_bias, nullptr, nullptr, nullptr, nullptr, C_, 576, nullptr);
        dwconv_k<<<dim3(1152,9), 256, 0, stream>>>(C_, qkv_dw_w, qkv_dw_b, D_);
        nacc_k<<<144, 384, 0, stream>>>(D_, nacc);
        attnscore_k<<<dim3(144,4), 256, 0, stream>>>(D_, araw);
        softmax_w2_k<<<4, 256, 0, stream>>>(araw, nacc, temperature, attn_out_w, W2);
        // G2: x2 = W2 @ v + attn_out_b + x   (in-place over xn; residual recovered from xn)
        gemm_k<64,false,false,false,1,false><<<dim3(3,288), 256, 0, stream>>>(
            W2, 0, 192, 3, D_ + 384, 576, attn_out_b, A_, st1b, nullptr, nullptr, A_, 192, nullptr);

        stat2_k<<<288, 192, 0, stream>>>(A_, s2s, s2q);
        fin2_k<<<1, 192, 0, stream>>>(s2s, s2q, s2m, s2r);

        // GDFN in two m-halves (t2half interleaved y1/y2 pairs)
        gemm_k<128,true,false,true,0,false><<<dim3(4,288), 256, 0, stream>>>(
            proj_in_w, 0, 192, 3, A_, 192, proj_in_b, nullptr, nullptr, s2m, s2r, D_, 512, nullptr);
        gate_k<<<dim3(1152,4), 256, 0, stream>>>(D_, dw_w, dw_b, C_, 0);
        gemm_k<128,true,false,true,0,false><<<dim3(4,288), 256, 0, stream>>>(
            proj_in_w, 512, 192, 3, A_, 192, proj_in_b, nullptr, nullptr, s2m, s2r, D_, 512, nullptr);
        gate_k<<<dim3(1152,4), 256, 0, stream>>>(D_, dw_w, dw_b, C_, 256);

        // G4: out = x2 + g @ proj_out_w^T + proj_out_b, transposed f32 write
        gemm_k<64,false,true,false,2,true><<<dim3(3,288), 256, 0, stream>>>(
            proj_out_w, 0, 510, 8, C_, 512, proj_out_b, A_, nullptr, nullptr, nullptr, nullptr, 0, outb);
    }
}

// Round 4
// 742.856 us; speedup vs baseline: 1.8543x; 1.3146x over previous
//
#include <hip/hip_runtime.h>
#include <math.h>

#define HW 36864
#define IMGW 192

typedef unsigned short u16;
typedef __attribute__((ext_vector_type(8))) short short8;
typedef __attribute__((ext_vector_type(8))) unsigned short ushort8;
typedef __attribute__((ext_vector_type(16))) float f32x16;

__device__ __forceinline__ float b2f(u16 u){ return __uint_as_float(((unsigned)u)<<16); }
__device__ __forceinline__ u16 f2b(float f){
    unsigned u = __float_as_uint(f);
    return (u16)((u + 0x7FFFu + ((u>>16)&1u)) >> 16);   // RNE
}
__device__ __forceinline__ int perm1020(int m){ return (m&1) ? 510+(m>>1) : (m>>1); }
__device__ __forceinline__ float gelu_exact(float x){
    return 0.5f * x * (1.f + erff(x * 0.70710678118654752f));
}
// async global->LDS, 16B per lane; LDS dest = wave-uniform base + lane*16
__device__ __forceinline__ void gll16(const u16* g, u16* l){
    __builtin_amdgcn_global_load_lds(
        (const __attribute__((address_space(1))) void*)g,
        (__attribute__((address_space(3))) void*)l, 16, 0, 0);
}

// ---------------- zero small buffer ----------------
__global__ __launch_bounds__(256)
void zero_k(float* __restrict__ p, int n)
{
    int i = blockIdx.x * 256 + threadIdx.x;
    if (i < n) p[i] = 0.f;
}

// ---------------- instance norm stats over f32 [row][HW]: (mean, rsqrt, -, -) ----------------
__global__ __launch_bounds__(256)
void stats_k(const float* __restrict__ x, float4* __restrict__ stats)
{
    int row = blockIdx.x;
    const float* p = x + (long)row * HW;
    float s = 0.f, s2 = 0.f;
    for (int i = threadIdx.x; i < HW/4; i += 256) {
        float4 v = reinterpret_cast<const float4*>(p)[i];
        s  += v.x + v.y + v.z + v.w;
        s2 += v.x*v.x + v.y*v.y + v.z*v.z + v.w*v.w;
    }
    for (int off = 32; off; off >>= 1) { s += __shfl_down(s, off); s2 += __shfl_down(s2, off); }
    __shared__ float ws[4], ws2[4];
    int lane = threadIdx.x & 63, wv = threadIdx.x >> 6;
    if (lane == 0) { ws[wv] = s; ws2[wv] = s2; }
    __syncthreads();
    if (threadIdx.x == 0) {
        float S = 0.f, S2 = 0.f;
        for (int w = 0; w < 4; ++w) { S += ws[w]; S2 += ws2[w]; }
        float mean = S / (float)HW;
        float var  = S2 / (float)HW - mean*mean;
        stats[row] = make_float4(mean, rsqrtf(var + 1e-5f), 0.f, 0.f);
    }
}

// ---------------- prep1: fold norm into qkv_w -> bf16 [640][192] + bias' [640] ----------------
__global__ __launch_bounds__(192)
void prep1_k(const float* __restrict__ w, const float* __restrict__ b,
             const float4* __restrict__ st, u16* __restrict__ wo, float* __restrict__ bo)
{
    int m = blockIdx.x, k = threadIdx.x;
    float4 s = st[k];
    float wv = (m < 576) ? w[(long)m*192 + k] * s.y : 0.f;
    u16 wb = f2b(wv);
    wo[(long)m*192 + k] = wb;
    float contrib = b2f(wb) * s.x;
    for (int off = 32; off; off >>= 1) contrib += __shfl_down(contrib, off);
    __shared__ float red[3];
    if ((k & 63) == 0) red[k >> 6] = contrib;
    __syncthreads();
    if (k == 0) bo[m] = ((m < 576) ? b[m] : 0.f) - (red[0] + red[1] + red[2]);
}

// ---------------- prep2: fold norm into proj_in_w (permuted rows) -> bf16 [1024][192] ----------------
__global__ __launch_bounds__(192)
void prep2_k(const float* __restrict__ w, const float* __restrict__ b,
             const float* __restrict__ s2m, const float* __restrict__ s2r,
             u16* __restrict__ wo, float* __restrict__ bo)
{
    int m = blockIdx.x, k = threadIdx.x;
    bool valid = (m < 1020);
    int src = valid ? perm1020(m) : 0;
    float wv = valid ? w[(long)src*192 + k] * s2r[k] : 0.f;
    u16 wb = f2b(wv);
    wo[(long)m*192 + k] = wb;
    float contrib = b2f(wb) * s2m[k];
    for (int off = 32; off; off >>= 1) contrib += __shfl_down(contrib, off);
    __shared__ float red[3];
    if ((k & 63) == 0) red[k >> 6] = contrib;
    __syncthreads();
    if (k == 0) bo[m] = (valid ? b[src] : 0.f) - (red[0] + red[1] + red[2]);
}

// ---------------- prep3: proj_out -> bf16 [192][512] (K padded 510->512) ----------------
__global__ __launch_bounds__(256)
void prep3_k(const float* __restrict__ w, u16* __restrict__ wo)
{
    int m = blockIdx.x;
    for (int k = threadIdx.x; k < 512; k += 256)
        wo[(long)m*512 + k] = (k < 510) ? f2b(w[(long)m*510 + k]) : (u16)0;
}

// ---------------- transpose: x[c][n] f32 -> xt[n][c] bf16 (per batch) ----------------
__global__ __launch_bounds__(256)
void tn_k(const float* __restrict__ xb, u16* __restrict__ xt)
{
    __shared__ float L[64 * 196];
    long n0 = (long)blockIdx.x * 64;
    int tid = threadIdx.x;
    #pragma unroll
    for (int i = 0; i < 48; ++i) {
        int idx = tid + i*256;          // 12288 = 64n x 192c
        int n = idx & 63, c = idx >> 6;
        L[n*196 + c] = xb[(long)c*HW + n0 + n];
    }
    __syncthreads();
    #pragma unroll
    for (int i = 0; i < 6; ++i) {
        int idx = tid + i*256;          // 1536 = 64n x 24oct
        int oc = idx % 24, n = idx / 24;
        ushort8 v;
        #pragma unroll
        for (int e = 0; e < 8; ++e) v[e] = f2b(L[n*196 + oc*8 + e]);
        *reinterpret_cast<ushort8*>(xt + (n0+n)*192 + oc*8) = v;
    }
}

// ---------------- MFMA GEMM: out[n][m] = sum_k B[n][kbase+k] * W[m][k] ----------------
// 128n x BM tile, 4 waves (2n x 2m), 32x32x16 bf16, BK=64, global_load_lds staging
template<int BM, int RESID, bool OUTT>
__global__ __launch_bounds__(256)
void gemm_k(const u16* __restrict__ W, int Kpad, int K64,
            const u16* __restrict__ B, int brs, int kbase,
            const float* __restrict__ bias,
            const u16* __restrict__ Rs,
            u16* __restrict__ outA, int ors, int Mout,
            float* __restrict__ outT)
{
    constexpr int MR  = BM / 64;
    constexpr int OLS = BM + 8;
    constexpr int L_MAIN = 8192 + BM*64;
    constexpr int L_OUT  = 128*OLS;
    constexpr int LDSU = L_MAIN > L_OUT ? L_MAIN : L_OUT;
    __shared__ u16 lds[LDSU];
    u16* Xl = lds;              // [128][64] swizzled
    u16* Wl = lds + 8192;       // [BM][64]  swizzled

    const int tid = threadIdx.x;
    const int m0 = blockIdx.x * BM;
    const long nn0 = (long)blockIdx.y * 128;
    const int ln = tid & 63, wv = tid >> 6;
    const int wn = (wv >> 1) * 64;
    const int wm = (wv & 1) * (BM/2);
    const int l31 = ln & 31, l5 = ln >> 5;

    const u16* Bb = B + nn0*(long)brs + kbase;
    const u16* Wb = W + (long)m0*Kpad;

    f32x16 acc[2][MR];
    #pragma unroll
    for (int a = 0; a < 2; ++a)
        #pragma unroll
        for (int b = 0; b < MR; ++b)
            #pragma unroll
            for (int r = 0; r < 16; ++r) acc[a][b][r] = 0.f;

    for (int ks = 0; ks < K64; ++ks) {
        // stage X: 128 rows x 64k, inverse-swizzled source, linear LDS dest
        #pragma unroll
        for (int i = 0; i < 4; ++i) {
            int chunk = i*256 + tid;
            int row = chunk >> 3, o = chunk & 7;
            int op = o ^ ((row >> 1) & 7);
            gll16(Bb + (long)row*brs + ks*64 + op*8, Xl + chunk*8);
        }
        // stage W: BM rows x 64k
        #pragma unroll
        for (int i = 0; i < BM/32; ++i) {
            int chunk = i*256 + tid;
            int row = chunk >> 3, o = chunk & 7;
            int op = o ^ ((row >> 1) & 7);
            gll16(Wb + (long)row*Kpad + ks*64 + op*8, Wl + chunk*8);
        }
        __syncthreads();
        #pragma unroll
        for (int k16 = 0; k16 < 4; ++k16) {
            short8 af[2];
            #pragma unroll
            for (int nr = 0; nr < 2; ++nr) {
                int row = wn + nr*32 + l31;
                int slot = (k16*2 + l5) ^ ((row >> 1) & 7);
                af[nr] = *reinterpret_cast<const short8*>(&Xl[row*64 + slot*8]);
            }
            short8 bf[MR];
            #pragma unroll
            for (int mr = 0; mr < MR; ++mr) {
                int rowm = wm + mr*32 + l31;
                int slot = (k16*2 + l5) ^ ((rowm >> 1) & 7);
                bf[mr] = *reinterpret_cast<const short8*>(&Wl[rowm*64 + slot*8]);
            }
            #pragma unroll
            for (int nr = 0; nr < 2; ++nr)
                #pragma unroll
                for (int mr = 0; mr < MR; ++mr)
                    acc[nr][mr] = __builtin_amdgcn_mfma_f32_32x32x16_bf16(af[nr], bf[mr], acc[nr][mr], 0, 0, 0);
        }
        __syncthreads();
    }
    // ---- epilogue ----
    float bsv[MR];
    #pragma unroll
    for (int mr = 0; mr < MR; ++mr)
        bsv[mr] = bias[m0 + wm + mr*32 + l31];
    u16* Ol = lds;
    #pragma unroll
    for (int nr = 0; nr < 2; ++nr)
        #pragma unroll
        for (int mr = 0; mr < MR; ++mr)
            #pragma unroll
            for (int reg = 0; reg < 16; ++reg) {
                int r32 = (reg & 3) + 8*(reg >> 2) + 4*l5;
                int grow = wn + nr*32 + r32;
                int gcol = wm + mr*32 + l31;
                float val = acc[nr][mr][reg] + bsv[mr];
                if (RESID == 2)
                    val += b2f(Rs[(nn0 + grow)*192 + m0 + gcol]);
                Ol[grow*OLS + gcol] = f2b(val);
            }
    __syncthreads();
    if (!OUTT) {
        constexpr int SPR = BM/8;
        #pragma unroll
        for (int i = 0; i < 128*SPR/256; ++i) {
            int idx = tid + i*256;
            int row = idx / SPR, sl = idx % SPR;
            if (m0 + sl*8 >= Mout) continue;
            ushort8 v = *reinterpret_cast<const ushort8*>(&Ol[row*OLS + sl*8]);
            if (RESID == 1) {
                ushort8 rv = *reinterpret_cast<const ushort8*>(Rs + (nn0+row)*(long)ors + m0 + sl*8);
                #pragma unroll
                for (int e = 0; e < 8; ++e) v[e] = f2b(b2f(v[e]) + b2f(rv[e]));
            }
            *reinterpret_cast<ushort8*>(outA + (nn0+row)*(long)ors + m0 + sl*8) = v;
        }
    } else {
        // transposed f32 output (BM=64 only): d_out[m][n]
        int m = tid >> 2, ng = tid & 3;
        float* orow = outT + (long)(m0 + m)*HW + nn0 + ng*32;
        #pragma unroll
        for (int i = 0; i < 32; i += 4) {
            float4 o;
            o.x = b2f(Ol[(ng*32+i+0)*OLS + m]);
            o.y = b2f(Ol[(ng*32+i+1)*OLS + m]);
            o.z = b2f(Ol[(ng*32+i+2)*OLS + m]);
            o.w = b2f(Ol[(ng*32+i+3)*OLS + m]);
            *reinterpret_cast<float4*>(orow + i) = o;
        }
    }
}

// ---------------- depthwise 3x3 channel-last [n][576] + fused q/k sumsq ----------------
__global__ __launch_bounds__(256)
void dwconv_k(const u16* __restrict__ in, const float* __restrict__ dww,
              const float* __restrict__ dwb, u16* __restrict__ out,
              float* __restrict__ nacc)
{
    __shared__ float wl[64][9];
    __shared__ float bl[64];
    __shared__ float nsum[64];
    int cg = blockIdx.y;
    int tid = threadIdx.x;
    for (int i = tid; i < 576; i += 256) { int ch = i/9, j = i%9; wl[ch][j] = dww[(cg*64+ch)*9 + j]; }
    if (tid < 64) { bl[tid] = dwb[cg*64 + tid]; nsum[tid] = 0.f; }
    __syncthreads();
    int pix = blockIdx.x*32 + (tid >> 3);
    int x = pix % IMGW, y = pix / IMGW;
    int cl = (tid & 7) * 8;
    int cb = cg*64 + cl;
    float a[8];
    #pragma unroll
    for (int e = 0; e < 8; ++e) a[e] = bl[cl+e];
    #pragma unroll
    for (int dy = -1; dy <= 1; ++dy) {
        int yy = y + dy;
        if (yy < 0 || yy >= IMGW) continue;
        #pragma unroll
        for (int dx = -1; dx <= 1; ++dx) {
            int xx = x + dx;
            if (xx < 0 || xx >= IMGW) continue;
            ushort8 v = *reinterpret_cast<const ushort8*>(in + (long)(yy*IMGW + xx)*576 + cb);
            int j = (dy+1)*3 + (dx+1);
            #pragma unroll
            for (int e = 0; e < 8; ++e) a[e] = fmaf(b2f(v[e]), wl[cl+e][j], a[e]);
        }
    }
    ushort8 o;
    #pragma unroll
    for (int e = 0; e < 8; ++e) o[e] = f2b(a[e]);
    *reinterpret_cast<ushort8*>(out + (long)pix*576 + cb) = o;
    if (cg < 6) {   // q/k channels: accumulate sum of squares
        #pragma unroll
        for (int e = 0; e < 8; ++e) {
            float s = a[e]*a[e];
            s += __shfl_xor(s, 8); s += __shfl_xor(s, 16); s += __shfl_xor(s, 32);
            if ((tid & 63) < 8) atomicAdd(&nsum[cl+e], s);
        }
        __syncthreads();
        if (tid < 64) atomicAdd(&nacc[cg*64 + tid], nsum[tid]);
    }
}

// ---------------- raw attention scores per head ----------------
__global__ __launch_bounds__(256)
void attnscore_k(const u16* __restrict__ qkvd, float* __restrict__ araw)
{
    __shared__ u16 T[96 * 264];
    int h = blockIdx.y;
    long nn0 = (long)blockIdx.x * 256;
    int tid = threadIdx.x;
    #pragma unroll
    for (int i = 0; i < 12; ++i) {
        int task = tid + i*256;            // 3072 = 256n x 12oct
        int oc = task % 12, n = task / 12;
        int cg = (oc < 6) ? (h*48 + oc*8) : (192 + h*48 + (oc-6)*8);
        ushort8 v = *reinterpret_cast<const ushort8*>(qkvd + (nn0+n)*576 + cg);
        int crow = oc*8;
        #pragma unroll
        for (int e = 0; e < 8; ++e) T[(crow+e)*264 + n] = v[e];
    }
    __syncthreads();
    int cg = tid >> 4, dg = tid & 15;
    float acc[3][3] = {{0.f,0.f,0.f},{0.f,0.f,0.f},{0.f,0.f,0.f}};
    for (int o = 0; o < 32; ++o) {
        float qf[3][8], kf[3][8];
        #pragma unroll
        for (int i = 0; i < 3; ++i) {
            short8 q = *reinterpret_cast<const short8*>(&T[(cg*3+i)*264 + o*8]);
            short8 k = *reinterpret_cast<const short8*>(&T[(48 + dg*3+i)*264 + o*8]);
            #pragma unroll
            for (int e = 0; e < 8; ++e) { qf[i][e] = b2f((u16)q[e]); kf[i][e] = b2f((u16)k[e]); }
        }
        #pragma unroll
        for (int i = 0; i < 3; ++i)
            #pragma unroll
            for (int j = 0; j < 3; ++j)
                #pragma unroll
                for (int e = 0; e < 8; ++e)
                    acc[i][j] = fmaf(qf[i][e], kf[j][e], acc[i][j]);
    }
    float* ar = araw + h*2304;
    #pragma unroll
    for (int i = 0; i < 3; ++i)
        #pragma unroll
        for (int j = 0; j < 3; ++j)
            atomicAdd(&ar[(cg*3+i)*48 + dg*3+j], acc[i][j]);
}

// ---------------- softmax + fold into attn_out_w -> bf16 W2b [192][192] ----------------
__global__ __launch_bounds__(256)
void softmax_w2_k(const float* __restrict__ araw, const float* __restrict__ nacc,
                  const float* __restrict__ temp, const float* __restrict__ aow,
                  u16* __restrict__ W2b)
{
    int h = blockIdx.x;
    __shared__ float sm[48][48];
    const float* ar = araw + h*2304;
    float t = temp[h];
    int tid = threadIdx.x;
    if (tid < 48) {
        int c = tid;
        float qn = fmaxf(sqrtf(nacc[h*48 + c]), 1e-12f);
        float row[48];
        float mx = -1e30f;
        for (int d = 0; d < 48; ++d) {
            float kn = fmaxf(sqrtf(nacc[192 + h*48 + d]), 1e-12f);
            float v = ar[c*48 + d] * t / (qn * kn);
            row[d] = v; mx = fmaxf(mx, v);
        }
        float ssum = 0.f;
        for (int d = 0; d < 48; ++d) { float e = expf(row[d] - mx); row[d] = e; ssum += e; }
        float inv = 1.f / ssum;
        for (int d = 0; d < 48; ++d) sm[c][d] = row[d] * inv;
    }
    __syncthreads();
    for (int i = tid; i < 192*48; i += 256) {
        int o = i / 48, d = i % 48;
        float s = 0.f;
        const float* arow = aow + (long)o*192 + h*48;
        for (int c = 0; c < 48; ++c) s += arow[c] * sm[c][d];
        W2b[(long)o*192 + h*48 + d] = f2b(s);
    }
}

// ---------------- column stats over x2 [36864][192] bf16 ----------------
__global__ __launch_bounds__(192)
void stat2_k(const u16* __restrict__ x2, float* __restrict__ ss, float* __restrict__ sq)
{
    int c = threadIdx.x;
    long r0 = (long)blockIdx.x * 128;
    float s = 0.f, q = 0.f;
    for (int i = 0; i < 128; ++i) {
        float f = b2f(x2[(r0+i)*192 + c]);
        s += f; q += f*f;
    }
    atomicAdd(&ss[c], s);
    atomicAdd(&sq[c], q);
}

__global__ __launch_bounds__(192)
void fin2_k(const float* __restrict__ ss, const float* __restrict__ sq,
            float* __restrict__ m, float* __restrict__ r)
{
    int c = threadIdx.x;
    float mean = ss[c] / (float)HW;
    float var  = sq[c] / (float)HW - mean*mean;
    m[c] = mean;
    r[c] = rsqrtf(var + 1e-5f);
}

// ---------------- depthwise 3x3 on interleaved pairs + GELU gate ----------------
__global__ __launch_bounds__(256)
void gate_k(const u16* __restrict__ t2h, const float* __restrict__ dww,
            const float* __restrict__ dwb, u16* __restrict__ g, int jbase)
{
    __shared__ float w1l[64][9], w2l[64][9];
    __shared__ float b1l[64], b2l[64];
    int tid = threadIdx.x;
    int jg = blockIdx.y;     // 0..3 -> 64 j each
    for (int i = tid; i < 1152; i += 256) {
        int half = i >= 576;
        int ii = i - half*576;
        int jj = ii / 9, tap = ii % 9;
        int gj = jbase + jg*64 + jj;
        float w = (gj < 510) ? dww[(long)(half ? 510 + gj : gj)*9 + tap] : 0.f;
        if (half) w2l[jj][tap] = w; else w1l[jj][tap] = w;
    }
    if (tid < 64) {
        int gj = jbase + jg*64 + tid;
        b1l[tid] = (gj < 510) ? dwb[gj] : 0.f;
        b2l[tid] = (gj < 510) ? dwb[510 + gj] : 0.f;
    }
    __syncthreads();
    int pix = blockIdx.x*32 + (tid >> 3);
    int x = pix % IMGW, y = pix / IMGW;
    int jl = (tid & 7) * 8;
    float a1[8], a2[8];
    #pragma unroll
    for (int e = 0; e < 8; ++e) { a1[e] = b1l[jl+e]; a2[e] = b2l[jl+e]; }
    #pragma unroll
    for (int dy = -1; dy <= 1; ++dy) {
        int yy = y + dy;
        if (yy < 0 || yy >= IMGW) continue;
        #pragma unroll
        for (int dx = -1; dx <= 1; ++dx) {
            int xx = x + dx;
            if (xx < 0 || xx >= IMGW) continue;
            const u16* p = t2h + (long)(yy*IMGW + xx)*512 + (jg*64 + jl)*2;
            ushort8 v0 = *reinterpret_cast<const ushort8*>(p);
            ushort8 v1 = *reinterpret_cast<const ushort8*>(p + 8);
            int tap = (dy+1)*3 + (dx+1);
            #pragma unroll
            for (int e = 0; e < 4; ++e) {
                a1[e]   = fmaf(b2f(v0[2*e]),   w1l[jl+e][tap],   a1[e]);
                a2[e]   = fmaf(b2f(v0[2*e+1]), w2l[jl+e][tap],   a2[e]);
                a1[e+4] = fmaf(b2f(v1[2*e]),   w1l[jl+e+4][tap], a1[e+4]);
                a2[e+4] = fmaf(b2f(v1[2*e+1]), w2l[jl+e+4][tap], a2[e+4]);
            }
        }
    }
    ushort8 o;
    #pragma unroll
    for (int e = 0; e < 8; ++e) {
        int gj = jbase + jg*64 + jl + e;
        float val = (gj < 510) ? gelu_exact(a1[e]) * a2[e] : 0.f;
        o[e] = f2b(val);
    }
    *reinterpret_cast<ushort8*>(g + (long)pix*512 + jbase + jg*64 + jl) = o;
}

extern "C" void kernel_launch(void* const* d_in, const int* in_sizes, int n_in,
                              void* d_out, int out_size, void* d_ws, size_t ws_size,
                              hipStream_t stream) {
    const float* x           = (const float*)d_in[0];
    const float* qkv_w       = (const float*)d_in[1];
    const float* qkv_bias    = (const float*)d_in[2];
    const float* qkv_dw_w    = (const float*)d_in[3];
    const float* qkv_dw_b    = (const float*)d_in[4];
    const float* attn_out_w  = (const float*)d_in[5];
    const float* attn_out_b  = (const float*)d_in[6];
    const float* temperature = (const float*)d_in[7];
    const float* proj_in_w   = (const float*)d_in[8];
    const float* proj_in_b   = (const float*)d_in[9];
    const float* dw_w        = (const float*)d_in[10];
    const float* dw_b        = (const float*)d_in[11];
    const float* proj_out_w  = (const float*)d_in[12];
    const float* proj_out_b  = (const float*)d_in[13];
    float* out = (float*)d_out;
    char* ws = (char*)d_ws;

    // big slots (per-batch reuse)
    u16* A_ = (u16*)ws;                                   // [36864][192]  xt -> x2
    u16* C_ = (u16*)(ws + 14155776);                      // [36864][576]  t1 -> g
    u16* D_ = (u16*)(ws + 14155776 + 42467328);           // [36864][576]  qkvd -> t2half
    // weights / smalls
    char* wsm = ws + 99090432;
    u16* W1p = (u16*)(wsm);                    // 640*192
    u16* W2p = (u16*)(wsm + 245760);           // 1024*192
    u16* W3p = (u16*)(wsm + 245760 + 393216);  // 192*512
    u16* W2b = (u16*)(wsm + 835584);           // 192*192
    float* b1p = (float*)(wsm + 835584 + 73728);   // 640
    float* b2p = b1p + 640;                        // 1024
    float* S_  = b2p + 1024;
    float* nacc = S_;               // 384
    float* s2s  = S_ + 384;         // 192
    float* s2q  = S_ + 576;         // 192
    float* araw = S_ + 768;         // 9216   (zero range = 9984 floats)
    float* s2m  = S_ + 9984;        // 192
    float* s2r  = S_ + 10176;       // 192
    float4* st1 = (float4*)(S_ + 10368);  // 384 float4

    stats_k<<<384, 256, 0, stream>>>(x, st1);
    prep3_k<<<192, 256, 0, stream>>>(proj_out_w, W3p);

    for (int b = 0; b < 2; ++b) {
        const float* xb = x + (long)b * 192 * HW;
        float* outb = out + (long)b * 192 * HW;
        const float4* st1b = st1 + b * 192;

        zero_k<<<39, 256, 0, stream>>>(S_, 9984);
        prep1_k<<<640, 192, 0, stream>>>(qkv_w, qkv_bias, st1b, W1p, b1p);
        tn_k<<<576, 256, 0, stream>>>(xb, A_);

        // G1: t1[n][576] = xt @ W1p^T + b1p
        gemm_k<128,0,false><<<dim3(5,288), 256, 0, stream>>>(
            W1p, 192, 3, A_, 192, 0, b1p, nullptr, C_, 576, 576, nullptr);
        dwconv_k<<<dim3(1152,9), 256, 0, stream>>>(C_, qkv_dw_w, qkv_dw_b, D_, nacc);
        attnscore_k<<<dim3(144,4), 256, 0, stream>>>(D_, araw);
        softmax_w2_k<<<4, 256, 0, stream>>>(araw, nacc, temperature, attn_out_w, W2b);
        // G2: x2 = W2b @ v + attn_out_b + x   (in-place over xt)
        gemm_k<64,1,false><<<dim3(3,288), 256, 0, stream>>>(
            W2b, 192, 3, D_, 576, 384, attn_out_b, A_, A_, 192, 192, nullptr);

        stat2_k<<<288, 192, 0, stream>>>(A_, s2s, s2q);
        fin2_k<<<1, 192, 0, stream>>>(s2s, s2q, s2m, s2r);
        prep2_k<<<1024, 192, 0, stream>>>(proj_in_w, proj_in_b, s2m, s2r, W2p, b2p);

        // GDFN in two m-halves (interleaved y1/y2 pairs)
        gemm_k<128,0,false><<<dim3(4,288), 256, 0, stream>>>(
            W2p, 192, 3, A_, 192, 0, b2p, nullptr, D_, 512, 512, nullptr);
        gate_k<<<dim3(1152,4), 256, 0, stream>>>(D_, dw_w, dw_b, C_, 0);
        gemm_k<128,0,false><<<dim3(4,288), 256, 0, stream>>>(
            W2p + (long)512*192, 192, 3, A_, 192, 0, b2p + 512, nullptr, D_, 512, 512, nullptr);
        gate_k<<<dim3(1152,4), 256, 0, stream>>>(D_, dw_w, dw_b, C_, 256);

        // G4: out = x2 + g @ W3p^T + proj_out_b  (transposed f32 write)
        gemm_k<64,2,true><<<dim3(3,288), 256, 0, stream>>>(
            W3p, 512, 8, C_, 512, 0, proj_out_b, A_, nullptr, 0, 192, outb);
    }
}

// Round 5
// 605.777 us; speedup vs baseline: 2.2740x; 1.2263x over previous
//
#include <hip/hip_runtime.h>
#include <math.h>

#define HW 36864
#define IMGW 192

typedef unsigned short u16;
typedef __attribute__((ext_vector_type(8))) short short8;
typedef __attribute__((ext_vector_type(8))) unsigned short ushort8;
typedef __attribute__((ext_vector_type(16))) float f32x16;

__device__ __forceinline__ float b2f(u16 u){ return __uint_as_float(((unsigned)u)<<16); }
__device__ __forceinline__ u16 f2b(float f){
    unsigned u = __float_as_uint(f);
    return (u16)((u + 0x7FFFu + ((u>>16)&1u)) >> 16);   // RNE
}
__device__ __forceinline__ int perm1020(int m){ return (m&1) ? 510+(m>>1) : (m>>1); }
__device__ __forceinline__ float gelu_exact(float x){
    return 0.5f * x * (1.f + erff(x * 0.70710678118654752f));
}
// async global->LDS, 16B per lane; LDS dest = wave-uniform base + lane*16
__device__ __forceinline__ void gll16(const u16* g, u16* l){
    __builtin_amdgcn_global_load_lds(
        (const __attribute__((address_space(1))) void*)g,
        (__attribute__((address_space(3))) void*)l, 16, 0, 0);
}

// ---------------- zero small buffer ----------------
__global__ __launch_bounds__(256)
void zero_k(float* __restrict__ p, int n)
{
    int i = blockIdx.x * 256 + threadIdx.x;
    if (i < n) p[i] = 0.f;
}

// ---------------- instance norm stats over f32 [row][HW]: (mean, rsqrt, -, -) ----------------
__global__ __launch_bounds__(256)
void stats_k(const float* __restrict__ x, float4* __restrict__ stats)
{
    int row = blockIdx.x;
    const float* p = x + (long)row * HW;
    float s = 0.f, s2 = 0.f;
    for (int i = threadIdx.x; i < HW/4; i += 256) {
        float4 v = reinterpret_cast<const float4*>(p)[i];
        s  += v.x + v.y + v.z + v.w;
        s2 += v.x*v.x + v.y*v.y + v.z*v.z + v.w*v.w;
    }
    for (int off = 32; off; off >>= 1) { s += __shfl_down(s, off); s2 += __shfl_down(s2, off); }
    __shared__ float ws[4], ws2[4];
    int lane = threadIdx.x & 63, wv = threadIdx.x >> 6;
    if (lane == 0) { ws[wv] = s; ws2[wv] = s2; }
    __syncthreads();
    if (threadIdx.x == 0) {
        float S = 0.f, S2 = 0.f;
        for (int w = 0; w < 4; ++w) { S += ws[w]; S2 += ws2[w]; }
        float mean = S / (float)HW;
        float var  = S2 / (float)HW - mean*mean;
        stats[row] = make_float4(mean, rsqrtf(var + 1e-5f), 0.f, 0.f);
    }
}

// ---------------- prep1: fold norm into qkv_w -> bf16 [640][192] + bias' [640] ----------------
__global__ __launch_bounds__(192)
void prep1_k(const float* __restrict__ w, const float* __restrict__ b,
             const float4* __restrict__ st, u16* __restrict__ wo, float* __restrict__ bo)
{
    int m = blockIdx.x, k = threadIdx.x;
    float4 s = st[k];
    float wv = (m < 576) ? w[(long)m*192 + k] * s.y : 0.f;
    u16 wb = f2b(wv);
    wo[(long)m*192 + k] = wb;
    float contrib = b2f(wb) * s.x;
    for (int off = 32; off; off >>= 1) contrib += __shfl_down(contrib, off);
    __shared__ float red[3];
    if ((k & 63) == 0) red[k >> 6] = contrib;
    __syncthreads();
    if (k == 0) bo[m] = ((m < 576) ? b[m] : 0.f) - (red[0] + red[1] + red[2]);
}

// ---------------- prep2: fold norm into proj_in_w (permuted rows) -> bf16 [1024][192] ----------------
__global__ __launch_bounds__(192)
void prep2_k(const float* __restrict__ w, const float* __restrict__ b,
             const float* __restrict__ s2m, const float* __restrict__ s2r,
             u16* __restrict__ wo, float* __restrict__ bo)
{
    int m = blockIdx.x, k = threadIdx.x;
    bool valid = (m < 1020);
    int src = valid ? perm1020(m) : 0;
    float wv = valid ? w[(long)src*192 + k] * s2r[k] : 0.f;
    u16 wb = f2b(wv);
    wo[(long)m*192 + k] = wb;
    float contrib = b2f(wb) * s2m[k];
    for (int off = 32; off; off >>= 1) contrib += __shfl_down(contrib, off);
    __shared__ float red[3];
    if ((k & 63) == 0) red[k >> 6] = contrib;
    __syncthreads();
    if (k == 0) bo[m] = (valid ? b[src] : 0.f) - (red[0] + red[1] + red[2]);
}

// ---------------- prep3: proj_out -> bf16 [192][512] (K padded 510->512) ----------------
__global__ __launch_bounds__(256)
void prep3_k(const float* __restrict__ w, u16* __restrict__ wo)
{
    int m = blockIdx.x;
    for (int k = threadIdx.x; k < 512; k += 256)
        wo[(long)m*512 + k] = (k < 510) ? f2b(w[(long)m*510 + k]) : (u16)0;
}

// ---------------- transpose: x[c][n] f32 -> xt[n][c] bf16 (per batch) ----------------
__global__ __launch_bounds__(256)
void tn_k(const float* __restrict__ xb, u16* __restrict__ xt)
{
    __shared__ float L[64 * 196];
    long n0 = (long)blockIdx.x * 64;
    int tid = threadIdx.x;
    #pragma unroll
    for (int i = 0; i < 48; ++i) {
        int idx = tid + i*256;          // 12288 = 64n x 192c
        int n = idx & 63, c = idx >> 6;
        L[n*196 + c] = xb[(long)c*HW + n0 + n];
    }
    __syncthreads();
    #pragma unroll
    for (int i = 0; i < 6; ++i) {
        int idx = tid + i*256;          // 1536 = 64n x 24oct
        int oc = idx % 24, n = idx / 24;
        ushort8 v;
        #pragma unroll
        for (int e = 0; e < 8; ++e) v[e] = f2b(L[n*196 + oc*8 + e]);
        *reinterpret_cast<ushort8*>(xt + (n0+n)*192 + oc*8) = v;
    }
}

// ---------------- MFMA GEMM: out[n][m] = sum_k B[n][kbase+k] * W[m][k] ----------------
// 128n x BM tile, 4 waves (2n x 2m), 32x32x16 bf16, BK=64, global_load_lds staging
template<int BM, int RESID, bool OUTT>
__global__ __launch_bounds__(256)
void gemm_k(const u16* __restrict__ W, int Kpad, int K64,
            const u16* __restrict__ B, int brs, int kbase,
            const float* __restrict__ bias,
            const u16* __restrict__ Rs,
            u16* __restrict__ outA, int ors, int Mout,
            float* __restrict__ outT)
{
    constexpr int MR  = BM / 64;
    constexpr int OLS = BM + 8;
    constexpr int L_MAIN = 8192 + BM*64;
    constexpr int L_OUT  = 128*OLS;
    constexpr int LDSU = L_MAIN > L_OUT ? L_MAIN : L_OUT;
    __shared__ u16 lds[LDSU];
    u16* Xl = lds;              // [128][64] swizzled
    u16* Wl = lds + 8192;       // [BM][64]  swizzled

    const int tid = threadIdx.x;
    const int m0 = blockIdx.x * BM;
    const long nn0 = (long)blockIdx.y * 128;
    const int ln = tid & 63, wv = tid >> 6;
    const int wn = (wv >> 1) * 64;
    const int wm = (wv & 1) * (BM/2);
    const int l31 = ln & 31, l5 = ln >> 5;

    const u16* Bb = B + nn0*(long)brs + kbase;
    const u16* Wb = W + (long)m0*Kpad;

    f32x16 acc[2][MR];
    #pragma unroll
    for (int a = 0; a < 2; ++a)
        #pragma unroll
        for (int b = 0; b < MR; ++b)
            #pragma unroll
            for (int r = 0; r < 16; ++r) acc[a][b][r] = 0.f;

    for (int ks = 0; ks < K64; ++ks) {
        // stage X: 128 rows x 64k, inverse-swizzled source, linear LDS dest
        #pragma unroll
        for (int i = 0; i < 4; ++i) {
            int chunk = i*256 + tid;
            int row = chunk >> 3, o = chunk & 7;
            int op = o ^ ((row >> 1) & 7);
            gll16(Bb + (long)row*brs + ks*64 + op*8, Xl + chunk*8);
        }
        // stage W: BM rows x 64k
        #pragma unroll
        for (int i = 0; i < BM/32; ++i) {
            int chunk = i*256 + tid;
            int row = chunk >> 3, o = chunk & 7;
            int op = o ^ ((row >> 1) & 7);
            gll16(Wb + (long)row*Kpad + ks*64 + op*8, Wl + chunk*8);
        }
        __syncthreads();
        #pragma unroll
        for (int k16 = 0; k16 < 4; ++k16) {
            short8 af[2];
            #pragma unroll
            for (int nr = 0; nr < 2; ++nr) {
                int row = wn + nr*32 + l31;
                int slot = (k16*2 + l5) ^ ((row >> 1) & 7);
                af[nr] = *reinterpret_cast<const short8*>(&Xl[row*64 + slot*8]);
            }
            short8 bf[MR];
            #pragma unroll
            for (int mr = 0; mr < MR; ++mr) {
                int rowm = wm + mr*32 + l31;
                int slot = (k16*2 + l5) ^ ((rowm >> 1) & 7);
                bf[mr] = *reinterpret_cast<const short8*>(&Wl[rowm*64 + slot*8]);
            }
            #pragma unroll
            for (int nr = 0; nr < 2; ++nr)
                #pragma unroll
                for (int mr = 0; mr < MR; ++mr)
                    acc[nr][mr] = __builtin_amdgcn_mfma_f32_32x32x16_bf16(af[nr], bf[mr], acc[nr][mr], 0, 0, 0);
        }
        __syncthreads();
    }
    // ---- epilogue ----
    float bsv[MR];
    #pragma unroll
    for (int mr = 0; mr < MR; ++mr)
        bsv[mr] = bias[m0 + wm + mr*32 + l31];
    u16* Ol = lds;
    #pragma unroll
    for (int nr = 0; nr < 2; ++nr)
        #pragma unroll
        for (int mr = 0; mr < MR; ++mr)
            #pragma unroll
            for (int reg = 0; reg < 16; ++reg) {
                int r32 = (reg & 3) + 8*(reg >> 2) + 4*l5;
                int grow = wn + nr*32 + r32;
                int gcol = wm + mr*32 + l31;
                float val = acc[nr][mr][reg] + bsv[mr];
                if (RESID == 2)
                    val += b2f(Rs[(nn0 + grow)*192 + m0 + gcol]);
                Ol[grow*OLS + gcol] = f2b(val);
            }
    __syncthreads();
    if (!OUTT) {
        constexpr int SPR = BM/8;
        #pragma unroll
        for (int i = 0; i < 128*SPR/256; ++i) {
            int idx = tid + i*256;
            int row = idx / SPR, sl = idx % SPR;
            if (m0 + sl*8 >= Mout) continue;
            ushort8 v = *reinterpret_cast<const ushort8*>(&Ol[row*OLS + sl*8]);
            if (RESID == 1) {
                ushort8 rv = *reinterpret_cast<const ushort8*>(Rs + (nn0+row)*(long)ors + m0 + sl*8);
                #pragma unroll
                for (int e = 0; e < 8; ++e) v[e] = f2b(b2f(v[e]) + b2f(rv[e]));
            }
            *reinterpret_cast<ushort8*>(outA + (nn0+row)*(long)ors + m0 + sl*8) = v;
        }
    } else {
        // transposed f32 output (BM=64 only): d_out[m][n]
        int m = tid >> 2, ng = tid & 3;
        float* orow = outT + (long)(m0 + m)*HW + nn0 + ng*32;
        #pragma unroll
        for (int i = 0; i < 32; i += 4) {
            float4 o;
            o.x = b2f(Ol[(ng*32+i+0)*OLS + m]);
            o.y = b2f(Ol[(ng*32+i+1)*OLS + m]);
            o.z = b2f(Ol[(ng*32+i+2)*OLS + m]);
            o.w = b2f(Ol[(ng*32+i+3)*OLS + m]);
            *reinterpret_cast<float4*>(orow + i) = o;
        }
    }
}

// ---------------- depthwise 3x3, LDS-tiled: 64ch x (8y x 32x) tile + fused q/k sumsq ----------------
__global__ __launch_bounds__(256)
void dwconv_k(const u16* __restrict__ in, const float* __restrict__ dww,
              const float* __restrict__ dwb, u16* __restrict__ out,
              float* __restrict__ nacc)
{
    __shared__ u16 T[10*34*64];        // 43520 B, [(r*34+c)*64 + ch]
    __shared__ float wl[64][9];
    __shared__ float bl[64];
    __shared__ float nsum[64];
    const int tid = threadIdx.x;
    const int cg = blockIdx.y;                       // 0..8
    const int ty = blockIdx.x / 6, tx = blockIdx.x % 6;
    const int y0 = ty*8, x0 = tx*32;

    for (int i = tid; i < 576; i += 256) wl[i/9][i%9] = dww[cg*576 + i];
    if (tid < 64) { bl[tid] = dwb[cg*64 + tid]; nsum[tid] = 0.f; }
    // stage tile + halo (zero-fill OOB)
    for (int i = tid; i < 2720; i += 256) {          // 10*34 px * 8 oct
        int r = i / 272;
        int rem = i - r*272;
        int c = rem >> 3, o = rem & 7;
        int gy = y0 - 1 + r, gx = x0 - 1 + c;
        ushort8 v = (ushort8)0;
        if ((unsigned)gy < 192u && (unsigned)gx < 192u)
            v = *reinterpret_cast<const ushort8*>(in + ((long)gy*192 + gx)*576 + cg*64 + o*8);
        *reinterpret_cast<ushort8*>(&T[i*8]) = v;
    }
    __syncthreads();

    const int o = tid & 7, xc = tid >> 3;            // oct, x-col
    float wr[9][8], bs[8];
    #pragma unroll
    for (int j = 0; j < 9; ++j)
        #pragma unroll
        for (int e = 0; e < 8; ++e) wr[j][e] = wl[o*8+e][j];
    #pragma unroll
    for (int e = 0; e < 8; ++e) bs[e] = bl[o*8+e];

    float sq[8] = {0.f,0.f,0.f,0.f,0.f,0.f,0.f,0.f};
    #pragma unroll
    for (int y = 0; y < 8; ++y) {
        float a[8];
        #pragma unroll
        for (int e = 0; e < 8; ++e) a[e] = bs[e];
        #pragma unroll
        for (int dy = 0; dy < 3; ++dy)
            #pragma unroll
            for (int dx = 0; dx < 3; ++dx) {
                ushort8 v = *reinterpret_cast<const ushort8*>(&T[((y+dy)*34 + xc+dx)*64 + o*8]);
                const int j = dy*3 + dx;
                #pragma unroll
                for (int e = 0; e < 8; ++e) a[e] = fmaf(b2f(v[e]), wr[j][e], a[e]);
            }
        ushort8 ov;
        #pragma unroll
        for (int e = 0; e < 8; ++e) { ov[e] = f2b(a[e]); sq[e] = fmaf(a[e], a[e], sq[e]); }
        *reinterpret_cast<ushort8*>(out + ((long)(y0+y)*192 + x0+xc)*576 + cg*64 + o*8) = ov;
    }
    if (cg < 6) {   // q/k channels: accumulate sum of squares
        #pragma unroll
        for (int e = 0; e < 8; ++e) {
            float s = sq[e];
            s += __shfl_xor(s, 8); s += __shfl_xor(s, 16); s += __shfl_xor(s, 32);
            if ((tid & 63) < 8) atomicAdd(&nsum[o*8 + e], s);
        }
        __syncthreads();
        if (tid < 64) atomicAdd(&nacc[cg*64 + tid], nsum[tid]);
    }
}

// ---------------- raw attention scores per head ----------------
__global__ __launch_bounds__(256)
void attnscore_k(const u16* __restrict__ qkvd, float* __restrict__ araw)
{
    __shared__ u16 T[96 * 264];
    int h = blockIdx.y;
    long nn0 = (long)blockIdx.x * 256;
    int tid = threadIdx.x;
    #pragma unroll
    for (int i = 0; i < 12; ++i) {
        int task = tid + i*256;            // 3072 = 256n x 12oct
        int oc = task % 12, n = task / 12;
        int cg = (oc < 6) ? (h*48 + oc*8) : (192 + h*48 + (oc-6)*8);
        ushort8 v = *reinterpret_cast<const ushort8*>(qkvd + (nn0+n)*576 + cg);
        int crow = oc*8;
        #pragma unroll
        for (int e = 0; e < 8; ++e) T[(crow+e)*264 + n] = v[e];
    }
    __syncthreads();
    int cg = tid >> 4, dg = tid & 15;
    float acc[3][3] = {{0.f,0.f,0.f},{0.f,0.f,0.f},{0.f,0.f,0.f}};
    for (int o = 0; o < 32; ++o) {
        float qf[3][8], kf[3][8];
        #pragma unroll
        for (int i = 0; i < 3; ++i) {
            short8 q = *reinterpret_cast<const short8*>(&T[(cg*3+i)*264 + o*8]);
            short8 k = *reinterpret_cast<const short8*>(&T[(48 + dg*3+i)*264 + o*8]);
            #pragma unroll
            for (int e = 0; e < 8; ++e) { qf[i][e] = b2f((u16)q[e]); kf[i][e] = b2f((u16)k[e]); }
        }
        #pragma unroll
        for (int i = 0; i < 3; ++i)
            #pragma unroll
            for (int j = 0; j < 3; ++j)
                #pragma unroll
                for (int e = 0; e < 8; ++e)
                    acc[i][j] = fmaf(qf[i][e], kf[j][e], acc[i][j]);
    }
    float* ar = araw + h*2304;
    #pragma unroll
    for (int i = 0; i < 3; ++i)
        #pragma unroll
        for (int j = 0; j < 3; ++j)
            atomicAdd(&ar[(cg*3+i)*48 + dg*3+j], acc[i][j]);
}

// ---------------- softmax + fold into attn_out_w -> bf16 W2b [192][192] ----------------
__global__ __launch_bounds__(256)
void softmax_w2_k(const float* __restrict__ araw, const float* __restrict__ nacc,
                  const float* __restrict__ temp, const float* __restrict__ aow,
                  u16* __restrict__ W2b)
{
    int h = blockIdx.x;
    __shared__ float sm[48][48];
    const float* ar = araw + h*2304;
    float t = temp[h];
    int tid = threadIdx.x;
    if (tid < 48) {
        int c = tid;
        float qn = fmaxf(sqrtf(nacc[h*48 + c]), 1e-12f);
        float row[48];
        float mx = -1e30f;
        for (int d = 0; d < 48; ++d) {
            float kn = fmaxf(sqrtf(nacc[192 + h*48 + d]), 1e-12f);
            float v = ar[c*48 + d] * t / (qn * kn);
            row[d] = v; mx = fmaxf(mx, v);
        }
        float ssum = 0.f;
        for (int d = 0; d < 48; ++d) { float e = expf(row[d] - mx); row[d] = e; ssum += e; }
        float inv = 1.f / ssum;
        for (int d = 0; d < 48; ++d) sm[c][d] = row[d] * inv;
    }
    __syncthreads();
    for (int i = tid; i < 192*48; i += 256) {
        int o = i / 48, d = i % 48;
        float s = 0.f;
        const float* arow = aow + (long)o*192 + h*48;
        for (int c = 0; c < 48; ++c) s += arow[c] * sm[c][d];
        W2b[(long)o*192 + h*48 + d] = f2b(s);
    }
}

// ---------------- column stats over x2 [36864][192] bf16 ----------------
__global__ __launch_bounds__(192)
void stat2_k(const u16* __restrict__ x2, float* __restrict__ ss, float* __restrict__ sq)
{
    int c = threadIdx.x;
    long r0 = (long)blockIdx.x * 128;
    float s = 0.f, q = 0.f;
    for (int i = 0; i < 128; ++i) {
        float f = b2f(x2[(r0+i)*192 + c]);
        s += f; q += f*f;
    }
    atomicAdd(&ss[c], s);
    atomicAdd(&sq[c], q);
}

__global__ __launch_bounds__(192)
void fin2_k(const float* __restrict__ ss, const float* __restrict__ sq,
            float* __restrict__ m, float* __restrict__ r)
{
    int c = threadIdx.x;
    float mean = ss[c] / (float)HW;
    float var  = sq[c] / (float)HW - mean*mean;
    m[c] = mean;
    r[c] = rsqrtf(var + 1e-5f);
}

// ---------------- gate: depthwise 3x3 on interleaved pairs + GELU, LDS-tiled ----------------
__global__ __launch_bounds__(256)
void gate_k(const u16* __restrict__ t2h, const float* __restrict__ dww,
            const float* __restrict__ dwb, u16* __restrict__ g, int jbase)
{
    __shared__ u16 T[10*34*64];        // 43520 B
    __shared__ float w1l[32][9], w2l[32][9];
    __shared__ float b1l[32], b2l[32];
    const int tid = threadIdx.x;
    const int cg = blockIdx.y;                       // 0..7 (64 u16 cols = 32 pairs)
    const int ty = blockIdx.x / 6, tx = blockIdx.x % 6;
    const int y0 = ty*8, x0 = tx*32;
    const int jb = jbase + cg*32;                    // global j of local pair 0

    for (int i = tid; i < 288; i += 256) {           // 32 pairs x 9 taps
        int p = i/9, j = i%9;
        int gj = jb + p;
        bool ok = (gj < 510);
        w1l[p][j] = ok ? dww[(long)gj*9 + j] : 0.f;
        w2l[p][j] = ok ? dww[(long)(510+gj)*9 + j] : 0.f;
    }
    if (tid < 32) {
        int gj = jb + tid;
        bool ok = (gj < 510);
        b1l[tid] = ok ? dwb[gj] : 0.f;
        b2l[tid] = ok ? dwb[510+gj] : 0.f;
    }
    for (int i = tid; i < 2720; i += 256) {
        int r = i / 272;
        int rem = i - r*272;
        int c = rem >> 3, o = rem & 7;
        int gy = y0 - 1 + r, gx = x0 - 1 + c;
        ushort8 v = (ushort8)0;
        if ((unsigned)gy < 192u && (unsigned)gx < 192u)
            v = *reinterpret_cast<const ushort8*>(t2h + ((long)gy*192 + gx)*512 + cg*64 + o*8);
        *reinterpret_cast<ushort8*>(&T[i*8]) = v;
    }
    __syncthreads();

    const int o = tid & 7, xc = tid >> 3;
    float w1r[4][9], w2r[4][9], b1r[4], b2r[4];
    #pragma unroll
    for (int p = 0; p < 4; ++p) {
        #pragma unroll
        for (int j = 0; j < 9; ++j) { w1r[p][j] = w1l[o*4+p][j]; w2r[p][j] = w2l[o*4+p][j]; }
        b1r[p] = b1l[o*4+p]; b2r[p] = b2l[o*4+p];
    }
    #pragma unroll
    for (int y = 0; y < 8; ++y) {
        float a1[4], a2[4];
        #pragma unroll
        for (int p = 0; p < 4; ++p) { a1[p] = b1r[p]; a2[p] = b2r[p]; }
        #pragma unroll
        for (int dy = 0; dy < 3; ++dy)
            #pragma unroll
            for (int dx = 0; dx < 3; ++dx) {
                ushort8 v = *reinterpret_cast<const ushort8*>(&T[((y+dy)*34 + xc+dx)*64 + o*8]);
                const int j = dy*3 + dx;
                #pragma unroll
                for (int p = 0; p < 4; ++p) {
                    a1[p] = fmaf(b2f(v[2*p]),   w1r[p][j], a1[p]);
                    a2[p] = fmaf(b2f(v[2*p+1]), w2r[p][j], a2[p]);
                }
            }
        ushort4 ov;
        ov.x = f2b(gelu_exact(a1[0]) * a2[0]);
        ov.y = f2b(gelu_exact(a1[1]) * a2[1]);
        ov.z = f2b(gelu_exact(a1[2]) * a2[2]);
        ov.w = f2b(gelu_exact(a1[3]) * a2[3]);
        *reinterpret_cast<ushort4*>(g + ((long)(y0+y)*192 + x0+xc)*512 + jb + o*4) = ov;
    }
}

extern "C" void kernel_launch(void* const* d_in, const int* in_sizes, int n_in,
                              void* d_out, int out_size, void* d_ws, size_t ws_size,
                              hipStream_t stream) {
    const float* x           = (const float*)d_in[0];
    const float* qkv_w       = (const float*)d_in[1];
    const float* qkv_bias    = (const float*)d_in[2];
    const float* qkv_dw_w    = (const float*)d_in[3];
    const float* qkv_dw_b    = (const float*)d_in[4];
    const float* attn_out_w  = (const float*)d_in[5];
    const float* attn_out_b  = (const float*)d_in[6];
    const float* temperature = (const float*)d_in[7];
    const float* proj_in_w   = (const float*)d_in[8];
    const float* proj_in_b   = (const float*)d_in[9];
    const float* dw_w        = (const float*)d_in[10];
    const float* dw_b        = (const float*)d_in[11];
    const float* proj_out_w  = (const float*)d_in[12];
    const float* proj_out_b  = (const float*)d_in[13];
    float* out = (float*)d_out;
    char* ws = (char*)d_ws;

    // big slots (per-batch reuse)
    u16* A_ = (u16*)ws;                                   // [36864][192]  xt -> x2
    u16* C_ = (u16*)(ws + 14155776);                      // [36864][576]  t1 -> g
    u16* D_ = (u16*)(ws + 14155776 + 42467328);           // [36864][576]  qkvd -> t2half
    // weights / smalls
    char* wsm = ws + 99090432;
    u16* W1p = (u16*)(wsm);                    // 640*192
    u16* W2p = (u16*)(wsm + 245760);           // 1024*192
    u16* W3p = (u16*)(wsm + 245760 + 393216);  // 192*512
    u16* W2b = (u16*)(wsm + 835584);           // 192*192
    float* b1p = (float*)(wsm + 835584 + 73728);   // 640
    float* b2p = b1p + 640;                        // 1024
    float* S_  = b2p + 1024;
    float* nacc = S_;               // 384
    float* s2s  = S_ + 384;         // 192
    float* s2q  = S_ + 576;         // 192
    float* araw = S_ + 768;         // 9216   (zero range = 9984 floats)
    float* s2m  = S_ + 9984;        // 192
    float* s2r  = S_ + 10176;       // 192
    float4* st1 = (float4*)(S_ + 10368);  // 384 float4

    stats_k<<<384, 256, 0, stream>>>(x, st1);
    prep3_k<<<192, 256, 0, stream>>>(proj_out_w, W3p);

    for (int b = 0; b < 2; ++b) {
        const float* xb = x + (long)b * 192 * HW;
        float* outb = out + (long)b * 192 * HW;
        const float4* st1b = st1 + b * 192;

        zero_k<<<39, 256, 0, stream>>>(S_, 9984);
        prep1_k<<<640, 192, 0, stream>>>(qkv_w, qkv_bias, st1b, W1p, b1p);
        tn_k<<<576, 256, 0, stream>>>(xb, A_);

        // G1: t1[n][576] = xt @ W1p^T + b1p
        gemm_k<128,0,false><<<dim3(5,288), 256, 0, stream>>>(
            W1p, 192, 3, A_, 192, 0, b1p, nullptr, C_, 576, 576, nullptr);
        dwconv_k<<<dim3(144,9), 256, 0, stream>>>(C_, qkv_dw_w, qkv_dw_b, D_, nacc);
        attnscore_k<<<dim3(144,4), 256, 0, stream>>>(D_, araw);
        softmax_w2_k<<<4, 256, 0, stream>>>(araw, nacc, temperature, attn_out_w, W2b);
        // G2: x2 = W2b @ v + attn_out_b + x   (in-place over xt)
        gemm_k<64,1,false><<<dim3(3,288), 256, 0, stream>>>(
            W2b, 192, 3, D_, 576, 384, attn_out_b, A_, A_, 192, 192, nullptr);

        stat2_k<<<288, 192, 0, stream>>>(A_, s2s, s2q);
        fin2_k<<<1, 192, 0, stream>>>(s2s, s2q, s2m, s2r);
        prep2_k<<<1024, 192, 0, stream>>>(proj_in_w, proj_in_b, s2m, s2r, W2p, b2p);

        // GDFN in two m-halves (interleaved y1/y2 pairs)
        gemm_k<128,0,false><<<dim3(4,288), 256, 0, stream>>>(
            W2p, 192, 3, A_, 192, 0, b2p, nullptr, D_, 512, 512, nullptr);
        gate_k<<<dim3(144,8), 256, 0, stream>>>(D_, dw_w, dw_b, C_, 0);
        gemm_k<128,0,false><<<dim3(4,288), 256, 0, stream>>>(
            W2p + (long)512*192, 192, 3, A_, 192, 0, b2p + 512, nullptr, D_, 512, 512, nullptr);
        gate_k<<<dim3(144,8), 256, 0, stream>>>(D_, dw_w, dw_b, C_, 256);

        // G4: out = x2 + g @ W3p^T + proj_out_b  (transposed f32 write)
        gemm_k<64,2,true><<<dim3(3,288), 256, 0, stream>>>(
            W3p, 512, 8, C_, 512, 0, proj_out_b, A_, nullptr, 0, 192, outb);
    }
}

// Round 6
// 514.906 us; speedup vs baseline: 2.6753x; 1.1765x over previous
//
#include <hip/hip_runtime.h>
#include <math.h>

#define HW 36864
#define IMGW 192

typedef unsigned short u16;
typedef __attribute__((ext_vector_type(8))) short short8;
typedef __attribute__((ext_vector_type(8))) unsigned short ushort8;
typedef __attribute__((ext_vector_type(16))) float f32x16;

__device__ __forceinline__ float b2f(u16 u){ return __uint_as_float(((unsigned)u)<<16); }
__device__ __forceinline__ u16 f2b(float f){
    unsigned u = __float_as_uint(f);
    return (u16)((u + 0x7FFFu + ((u>>16)&1u)) >> 16);   // RNE
}
__device__ __forceinline__ int perm1020(int m){ return (m&1) ? 510+(m>>1) : (m>>1); }
__device__ __forceinline__ float gelu_exact(float x){
    return 0.5f * x * (1.f + erff(x * 0.70710678118654752f));
}
// async global->LDS, 16B per lane; LDS dest = wave-uniform base + lane*16
__device__ __forceinline__ void gll16(const u16* g, u16* l){
    __builtin_amdgcn_global_load_lds(
        (const __attribute__((address_space(1))) void*)g,
        (__attribute__((address_space(3))) void*)l, 16, 0, 0);
}

// ---------------- zero small buffer ----------------
__global__ __launch_bounds__(256)
void zero_k(float* __restrict__ p, int n)
{
    int i = blockIdx.x * 256 + threadIdx.x;
    if (i < n) p[i] = 0.f;
}

// ---------------- instance norm stats over f32 [row][HW]: (mean, rsqrt, -, -) ----------------
__global__ __launch_bounds__(256)
void stats_k(const float* __restrict__ x, float4* __restrict__ stats)
{
    int row = blockIdx.x;
    const float* p = x + (long)row * HW;
    float s = 0.f, s2 = 0.f;
    for (int i = threadIdx.x; i < HW/4; i += 256) {
        float4 v = reinterpret_cast<const float4*>(p)[i];
        s  += v.x + v.y + v.z + v.w;
        s2 += v.x*v.x + v.y*v.y + v.z*v.z + v.w*v.w;
    }
    for (int off = 32; off; off >>= 1) { s += __shfl_down(s, off); s2 += __shfl_down(s2, off); }
    __shared__ float ws[4], ws2[4];
    int lane = threadIdx.x & 63, wv = threadIdx.x >> 6;
    if (lane == 0) { ws[wv] = s; ws2[wv] = s2; }
    __syncthreads();
    if (threadIdx.x == 0) {
        float S = 0.f, S2 = 0.f;
        for (int w = 0; w < 4; ++w) { S += ws[w]; S2 += ws2[w]; }
        float mean = S / (float)HW;
        float var  = S2 / (float)HW - mean*mean;
        stats[row] = make_float4(mean, rsqrtf(var + 1e-5f), 0.f, 0.f);
    }
}

// ---------------- prep1: fold norm into qkv_w -> bf16 [640][192] + bias' [640] ----------------
__global__ __launch_bounds__(192)
void prep1_k(const float* __restrict__ w, const float* __restrict__ b,
             const float4* __restrict__ st, u16* __restrict__ wo, float* __restrict__ bo)
{
    int m = blockIdx.x, k = threadIdx.x;
    float4 s = st[k];
    float wv = (m < 576) ? w[(long)m*192 + k] * s.y : 0.f;
    u16 wb = f2b(wv);
    wo[(long)m*192 + k] = wb;
    float contrib = b2f(wb) * s.x;
    for (int off = 32; off; off >>= 1) contrib += __shfl_down(contrib, off);
    __shared__ float red[3];
    if ((k & 63) == 0) red[k >> 6] = contrib;
    __syncthreads();
    if (k == 0) bo[m] = ((m < 576) ? b[m] : 0.f) - (red[0] + red[1] + red[2]);
}

// ---------------- prep2: fold norm into proj_in_w (permuted rows) -> bf16 [1024][192] ----------------
__global__ __launch_bounds__(192)
void prep2_k(const float* __restrict__ w, const float* __restrict__ b,
             const float* __restrict__ s2m, const float* __restrict__ s2r,
             u16* __restrict__ wo, float* __restrict__ bo)
{
    int m = blockIdx.x, k = threadIdx.x;
    bool valid = (m < 1020);
    int src = valid ? perm1020(m) : 0;
    float wv = valid ? w[(long)src*192 + k] * s2r[k] : 0.f;
    u16 wb = f2b(wv);
    wo[(long)m*192 + k] = wb;
    float contrib = b2f(wb) * s2m[k];
    for (int off = 32; off; off >>= 1) contrib += __shfl_down(contrib, off);
    __shared__ float red[3];
    if ((k & 63) == 0) red[k >> 6] = contrib;
    __syncthreads();
    if (k == 0) bo[m] = (valid ? b[src] : 0.f) - (red[0] + red[1] + red[2]);
}

// ---------------- prep3: proj_out -> bf16 [192][512] (K padded 510->512) ----------------
__global__ __launch_bounds__(256)
void prep3_k(const float* __restrict__ w, u16* __restrict__ wo)
{
    int m = blockIdx.x;
    for (int k = threadIdx.x; k < 512; k += 256)
        wo[(long)m*512 + k] = (k < 510) ? f2b(w[(long)m*510 + k]) : (u16)0;
}

// ---------------- transpose: x[c][n] f32 -> xt[n][c] bf16 (per batch) ----------------
__global__ __launch_bounds__(256)
void tn_k(const float* __restrict__ xb, u16* __restrict__ xt)
{
    __shared__ float L[64 * 196];
    long n0 = (long)blockIdx.x * 64;
    int tid = threadIdx.x;
    #pragma unroll
    for (int i = 0; i < 48; ++i) {
        int idx = tid + i*256;          // 12288 = 64n x 192c
        int n = idx & 63, c = idx >> 6;
        L[n*196 + c] = xb[(long)c*HW + n0 + n];
    }
    __syncthreads();
    #pragma unroll
    for (int i = 0; i < 6; ++i) {
        int idx = tid + i*256;          // 1536 = 64n x 24oct
        int oc = idx % 24, n = idx / 24;
        ushort8 v;
        #pragma unroll
        for (int e = 0; e < 8; ++e) v[e] = f2b(L[n*196 + oc*8 + e]);
        *reinterpret_cast<ushort8*>(xt + (n0+n)*192 + oc*8) = v;
    }
}

// ---------------- MFMA GEMM: out[n][m] = sum_k B[n][kbase+k] * W[m][k] ----------------
template<int BM, int RESID, bool OUTT>
__global__ __launch_bounds__(256)
void gemm_k(const u16* __restrict__ W, int Kpad, int K64,
            const u16* __restrict__ B, int brs, int kbase,
            const float* __restrict__ bias,
            const u16* __restrict__ Rs,
            u16* __restrict__ outA, int ors, int Mout,
            float* __restrict__ outT)
{
    constexpr int MR  = BM / 64;
    constexpr int OLS = BM + 8;
    constexpr int L_MAIN = 8192 + BM*64;
    constexpr int L_OUT  = 128*OLS;
    constexpr int LDSU = L_MAIN > L_OUT ? L_MAIN : L_OUT;
    __shared__ u16 lds[LDSU];
    u16* Xl = lds;              // [128][64] swizzled
    u16* Wl = lds + 8192;       // [BM][64]  swizzled

    const int tid = threadIdx.x;
    const int m0 = blockIdx.x * BM;
    const long nn0 = (long)blockIdx.y * 128;
    const int ln = tid & 63, wv = tid >> 6;
    const int wn = (wv >> 1) * 64;
    const int wm = (wv & 1) * (BM/2);
    const int l31 = ln & 31, l5 = ln >> 5;

    const u16* Bb = B + nn0*(long)brs + kbase;
    const u16* Wb = W + (long)m0*Kpad;

    f32x16 acc[2][MR];
    #pragma unroll
    for (int a = 0; a < 2; ++a)
        #pragma unroll
        for (int b = 0; b < MR; ++b)
            #pragma unroll
            for (int r = 0; r < 16; ++r) acc[a][b][r] = 0.f;

    for (int ks = 0; ks < K64; ++ks) {
        #pragma unroll
        for (int i = 0; i < 4; ++i) {
            int chunk = i*256 + tid;
            int row = chunk >> 3, o = chunk & 7;
            int op = o ^ ((row >> 1) & 7);
            gll16(Bb + (long)row*brs + ks*64 + op*8, Xl + chunk*8);
        }
        #pragma unroll
        for (int i = 0; i < BM/32; ++i) {
            int chunk = i*256 + tid;
            int row = chunk >> 3, o = chunk & 7;
            int op = o ^ ((row >> 1) & 7);
            gll16(Wb + (long)row*Kpad + ks*64 + op*8, Wl + chunk*8);
        }
        __syncthreads();
        #pragma unroll
        for (int k16 = 0; k16 < 4; ++k16) {
            short8 af[2];
            #pragma unroll
            for (int nr = 0; nr < 2; ++nr) {
                int row = wn + nr*32 + l31;
                int slot = (k16*2 + l5) ^ ((row >> 1) & 7);
                af[nr] = *reinterpret_cast<const short8*>(&Xl[row*64 + slot*8]);
            }
            short8 bf[MR];
            #pragma unroll
            for (int mr = 0; mr < MR; ++mr) {
                int rowm = wm + mr*32 + l31;
                int slot = (k16*2 + l5) ^ ((rowm >> 1) & 7);
                bf[mr] = *reinterpret_cast<const short8*>(&Wl[rowm*64 + slot*8]);
            }
            #pragma unroll
            for (int nr = 0; nr < 2; ++nr)
                #pragma unroll
                for (int mr = 0; mr < MR; ++mr)
                    acc[nr][mr] = __builtin_amdgcn_mfma_f32_32x32x16_bf16(af[nr], bf[mr], acc[nr][mr], 0, 0, 0);
        }
        __syncthreads();
    }
    float bsv[MR];
    #pragma unroll
    for (int mr = 0; mr < MR; ++mr)
        bsv[mr] = bias[m0 + wm + mr*32 + l31];
    u16* Ol = lds;
    #pragma unroll
    for (int nr = 0; nr < 2; ++nr)
        #pragma unroll
        for (int mr = 0; mr < MR; ++mr)
            #pragma unroll
            for (int reg = 0; reg < 16; ++reg) {
                int r32 = (reg & 3) + 8*(reg >> 2) + 4*l5;
                int grow = wn + nr*32 + r32;
                int gcol = wm + mr*32 + l31;
                float val = acc[nr][mr][reg] + bsv[mr];
                if (RESID == 2)
                    val += b2f(Rs[(nn0 + grow)*192 + m0 + gcol]);
                Ol[grow*OLS + gcol] = f2b(val);
            }
    __syncthreads();
    if (!OUTT) {
        constexpr int SPR = BM/8;
        #pragma unroll
        for (int i = 0; i < 128*SPR/256; ++i) {
            int idx = tid + i*256;
            int row = idx / SPR, sl = idx % SPR;
            if (m0 + sl*8 >= Mout) continue;
            ushort8 v = *reinterpret_cast<const ushort8*>(&Ol[row*OLS + sl*8]);
            if (RESID == 1) {
                ushort8 rv = *reinterpret_cast<const ushort8*>(Rs + (nn0+row)*(long)ors + m0 + sl*8);
                #pragma unroll
                for (int e = 0; e < 8; ++e) v[e] = f2b(b2f(v[e]) + b2f(rv[e]));
            }
            *reinterpret_cast<ushort8*>(outA + (nn0+row)*(long)ors + m0 + sl*8) = v;
        }
    } else {
        int m = tid >> 2, ng = tid & 3;
        float* orow = outT + (long)(m0 + m)*HW + nn0 + ng*32;
        #pragma unroll
        for (int i = 0; i < 32; i += 4) {
            float4 o;
            o.x = b2f(Ol[(ng*32+i+0)*OLS + m]);
            o.y = b2f(Ol[(ng*32+i+1)*OLS + m]);
            o.z = b2f(Ol[(ng*32+i+2)*OLS + m]);
            o.w = b2f(Ol[(ng*32+i+3)*OLS + m]);
            *reinterpret_cast<float4*>(orow + i) = o;
        }
    }
}

// ---------------- depthwise 3x3, LDS-tiled; q/k -> transposed qkT, v -> vbuf[n][192] ----------------
__global__ __launch_bounds__(256)
void dwconv_k(const u16* __restrict__ in, const float* __restrict__ dww,
              const float* __restrict__ dwb, u16* __restrict__ vbuf,
              u16* __restrict__ qkT, float* __restrict__ nacc)
{
    __shared__ u16 T[21760];           // 10*34*64 input tile; reused as T2[64][258]
    __shared__ float wl[64][9];
    __shared__ float bl[64];
    __shared__ float nsum[64];
    const int tid = threadIdx.x;
    const int cg = blockIdx.y;                       // 0..8
    const int ty = blockIdx.x / 6, tx = blockIdx.x % 6;
    const int y0 = ty*8, x0 = tx*32;
    const bool isv = (cg >= 6);

    for (int i = tid; i < 576; i += 256) wl[i/9][i%9] = dww[cg*576 + i];
    if (tid < 64) { bl[tid] = dwb[cg*64 + tid]; nsum[tid] = 0.f; }
    for (int i = tid; i < 2720; i += 256) {          // 10*34 px * 8 oct
        int r = i / 272;
        int rem = i - r*272;
        int c = rem >> 3, o = rem & 7;
        int gy = y0 - 1 + r, gx = x0 - 1 + c;
        ushort8 v = (ushort8)0;
        if ((unsigned)gy < 192u && (unsigned)gx < 192u)
            v = *reinterpret_cast<const ushort8*>(in + ((long)gy*192 + gx)*576 + cg*64 + o*8);
        *reinterpret_cast<ushort8*>(&T[i*8]) = v;
    }
    __syncthreads();

    const int o = tid & 7, xc = tid >> 3;            // oct, x-col
    float wr[9][8], bs[8];
    #pragma unroll
    for (int j = 0; j < 9; ++j)
        #pragma unroll
        for (int e = 0; e < 8; ++e) wr[j][e] = wl[o*8+e][j];
    #pragma unroll
    for (int e = 0; e < 8; ++e) bs[e] = bl[o*8+e];

    float sq[8] = {0.f,0.f,0.f,0.f,0.f,0.f,0.f,0.f};
    ushort8 ov[8];
    #pragma unroll
    for (int y = 0; y < 8; ++y) {
        float a[8];
        #pragma unroll
        for (int e = 0; e < 8; ++e) a[e] = bs[e];
        #pragma unroll
        for (int dy = 0; dy < 3; ++dy)
            #pragma unroll
            for (int dx = 0; dx < 3; ++dx) {
                ushort8 v = *reinterpret_cast<const ushort8*>(&T[((y+dy)*34 + xc+dx)*64 + o*8]);
                const int j = dy*3 + dx;
                #pragma unroll
                for (int e = 0; e < 8; ++e) a[e] = fmaf(b2f(v[e]), wr[j][e], a[e]);
            }
        #pragma unroll
        for (int e = 0; e < 8; ++e) { ov[y][e] = f2b(a[e]); sq[e] = fmaf(a[e], a[e], sq[e]); }
        if (isv)
            *reinterpret_cast<ushort8*>(vbuf + ((long)(y0+y)*192 + x0+xc)*192 + (cg-6)*64 + o*8) = ov[y];
    }
    if (!isv) {
        // fused q/k sum-of-squares
        #pragma unroll
        for (int e = 0; e < 8; ++e) {
            float s = sq[e];
            s += __shfl_xor(s, 8); s += __shfl_xor(s, 16); s += __shfl_xor(s, 32);
            if ((tid & 63) < 8) atomicAdd(&nsum[o*8 + e], s);
        }
        __syncthreads();                 // all T reads + nsum done
        if (tid < 64) atomicAdd(&nacc[cg*64 + tid], nsum[tid]);
        // transpose within tile: T2[ch][y*32+xc], stride 258 to spread banks
        #pragma unroll
        for (int y = 0; y < 8; ++y)
            #pragma unroll
            for (int e = 0; e < 8; ++e)
                T[(o*8+e)*258 + y*32 + xc] = ov[y][e];
        __syncthreads();
        // write out: 64 ch x 8 y x 4 sx chunks of 16B
        #pragma unroll
        for (int i = 0; i < 8; ++i) {
            int idx = i*256 + tid;           // ch*32 + yy*4 + sx
            int ch = idx >> 5, rem = idx & 31;
            int yy = rem >> 2, sx = rem & 3;
            ushort8 v = *reinterpret_cast<const ushort8*>(&T[ch*258 + yy*32 + sx*8]);
            *reinterpret_cast<ushort8*>(qkT + (long)(cg*64+ch)*HW + (long)(y0+yy)*192 + x0 + sx*8) = v;
        }
    }
}

// ---------------- MFMA attention scores: apart[ns][h][c*48+d] = sum_n q·k over n-chunk ----------------
__global__ __launch_bounds__(256)
void attnscore_k(const u16* __restrict__ qkT, float* __restrict__ apart)
{
    __shared__ u16 lds[8192];           // A[64][64] + B[64][64] swizzled
    u16* Al = lds;
    u16* Bl = lds + 4096;
    const int tid = threadIdx.x;
    const int h = blockIdx.y;
    const long nb = (long)blockIdx.x * 512;
    const int ln = tid & 63, wv = tid >> 6;
    const int wq = (wv >> 1) * 32, wd = (wv & 1) * 32;
    const int l31 = ln & 31, l5 = ln >> 5;

    f32x16 acc;
    #pragma unroll
    for (int r = 0; r < 16; ++r) acc[r] = 0.f;

    for (int ks = 0; ks < 8; ++ks) {
        #pragma unroll
        for (int i = 0; i < 2; ++i) {
            int chunk = i*256 + tid;         // 512 = 64 rows x 8 oct
            int row = chunk >> 3, o = chunk & 7;
            int op = o ^ ((row >> 1) & 7);
            int qr = h*48 + (row < 48 ? row : 0);
            gll16(qkT + (long)qr*HW + nb + ks*64 + op*8, Al + chunk*8);
        }
        #pragma unroll
        for (int i = 0; i < 2; ++i) {
            int chunk = i*256 + tid;
            int row = chunk >> 3, o = chunk & 7;
            int op = o ^ ((row >> 1) & 7);
            int kr = 192 + h*48 + (row < 48 ? row : 0);
            gll16(qkT + (long)kr*HW + nb + ks*64 + op*8, Bl + chunk*8);
        }
        __syncthreads();
        #pragma unroll
        for (int k16 = 0; k16 < 4; ++k16) {
            int rq = wq + l31;
            int sq_ = (k16*2 + l5) ^ ((rq >> 1) & 7);
            short8 af = *reinterpret_cast<const short8*>(&Al[rq*64 + sq_*8]);
            int rk = wd + l31;
            int sk = (k16*2 + l5) ^ ((rk >> 1) & 7);
            short8 bf = *reinterpret_cast<const short8*>(&Bl[rk*64 + sk*8]);
            acc = __builtin_amdgcn_mfma_f32_32x32x16_bf16(af, bf, acc, 0, 0, 0);
        }
        __syncthreads();
    }
    float* ap = apart + ((long)blockIdx.x*4 + h) * 2304;
    #pragma unroll
    for (int reg = 0; reg < 16; ++reg) {
        int c = wq + (reg & 3) + 8*(reg >> 2) + 4*l5;
        int d = wd + l31;
        if (c < 48 && d < 48) ap[c*48 + d] = acc[reg];
    }
}

// ---------------- reduce split-n partials ----------------
__global__ __launch_bounds__(256)
void red_k(const float* __restrict__ apart, float* __restrict__ araw)
{
    int idx = blockIdx.x*256 + threadIdx.x;   // 9216
    float s = 0.f;
    for (int p = 0; p < 72; ++p) s += apart[(long)p*9216 + idx];
    araw[idx] = s;
}

// ---------------- softmax (all heads, 1 block, register rows) -> ssm f32 ----------------
__global__ __launch_bounds__(256)
void softmax_sm_k(const float* __restrict__ araw, const float* __restrict__ nacc,
                  const float* __restrict__ temp, float* __restrict__ ssm)
{
    int tid = threadIdx.x;
    if (tid >= 192) return;
    int h = tid / 48, c = tid % 48;
    float qn = fmaxf(sqrtf(nacc[h*48 + c]), 1e-12f);
    float ti = temp[h] / qn;
    const float* ar = araw + h*2304 + c*48;
    const float* nk = nacc + 192 + h*48;
    float row[48];
    float mx = -1e30f;
    #pragma unroll
    for (int d = 0; d < 48; ++d) {
        float kn = fmaxf(sqrtf(nk[d]), 1e-12f);
        row[d] = ar[d] * ti / kn;
        mx = fmaxf(mx, row[d]);
    }
    float ssum = 0.f;
    #pragma unroll
    for (int d = 0; d < 48; ++d) { float e = expf(row[d] - mx); row[d] = e; ssum += e; }
    float inv = 1.f / ssum;
    float* so = ssm + h*2304 + c*48;
    #pragma unroll
    for (int d = 0; d < 48; ++d) so[d] = row[d] * inv;
}

// ---------------- fold softmax into attn_out_w -> bf16 W2b [192][192] ----------------
__global__ __launch_bounds__(256)
void w2fold_k(const float* __restrict__ ssm, const float* __restrict__ aow,
              u16* __restrict__ W2b)
{
    int idx = blockIdx.x*256 + threadIdx.x;    // 36864
    int o = idx / 192, col = idx % 192;
    int h = col / 48, d = col % 48;
    const float* ar = aow + (long)o*192 + h*48;
    const float* sp = ssm + h*2304 + d;
    float s = 0.f;
    #pragma unroll
    for (int c = 0; c < 48; ++c) s = fmaf(ar[c], sp[c*48], s);
    W2b[idx] = f2b(s);
}

// ---------------- column stats over x2 [36864][192] bf16 ----------------
__global__ __launch_bounds__(192)
void stat2_k(const u16* __restrict__ x2, float* __restrict__ ss, float* __restrict__ sq)
{
    int c = threadIdx.x;
    long r0 = (long)blockIdx.x * 128;
    float s = 0.f, q = 0.f;
    for (int i = 0; i < 128; ++i) {
        float f = b2f(x2[(r0+i)*192 + c]);
        s += f; q += f*f;
    }
    atomicAdd(&ss[c], s);
    atomicAdd(&sq[c], q);
}

__global__ __launch_bounds__(192)
void fin2_k(const float* __restrict__ ss, const float* __restrict__ sq,
            float* __restrict__ m, float* __restrict__ r)
{
    int c = threadIdx.x;
    float mean = ss[c] / (float)HW;
    float var  = sq[c] / (float)HW - mean*mean;
    m[c] = mean;
    r[c] = rsqrtf(var + 1e-5f);
}

// ---------------- gate: depthwise 3x3 on interleaved pairs + GELU, LDS-tiled ----------------
__global__ __launch_bounds__(256)
void gate_k(const u16* __restrict__ t2h, const float* __restrict__ dww,
            const float* __restrict__ dwb, u16* __restrict__ g, int jbase)
{
    __shared__ u16 T[10*34*64];        // 43520 B
    __shared__ float w1l[32][9], w2l[32][9];
    __shared__ float b1l[32], b2l[32];
    const int tid = threadIdx.x;
    const int cg = blockIdx.y;                       // 0..7
    const int ty = blockIdx.x / 6, tx = blockIdx.x % 6;
    const int y0 = ty*8, x0 = tx*32;
    const int jb = jbase + cg*32;

    for (int i = tid; i < 288; i += 256) {
        int p = i/9, j = i%9;
        int gj = jb + p;
        bool ok = (gj < 510);
        w1l[p][j] = ok ? dww[(long)gj*9 + j] : 0.f;
        w2l[p][j] = ok ? dww[(long)(510+gj)*9 + j] : 0.f;
    }
    if (tid < 32) {
        int gj = jb + tid;
        bool ok = (gj < 510);
        b1l[tid] = ok ? dwb[gj] : 0.f;
        b2l[tid] = ok ? dwb[510+gj] : 0.f;
    }
    for (int i = tid; i < 2720; i += 256) {
        int r = i / 272;
        int rem = i - r*272;
        int c = rem >> 3, o = rem & 7;
        int gy = y0 - 1 + r, gx = x0 - 1 + c;
        ushort8 v = (ushort8)0;
        if ((unsigned)gy < 192u && (unsigned)gx < 192u)
            v = *reinterpret_cast<const ushort8*>(t2h + ((long)gy*192 + gx)*512 + cg*64 + o*8);
        *reinterpret_cast<ushort8*>(&T[i*8]) = v;
    }
    __syncthreads();

    const int o = tid & 7, xc = tid >> 3;
    float w1r[4][9], w2r[4][9], b1r[4], b2r[4];
    #pragma unroll
    for (int p = 0; p < 4; ++p) {
        #pragma unroll
        for (int j = 0; j < 9; ++j) { w1r[p][j] = w1l[o*4+p][j]; w2r[p][j] = w2l[o*4+p][j]; }
        b1r[p] = b1l[o*4+p]; b2r[p] = b2l[o*4+p];
    }
    #pragma unroll
    for (int y = 0; y < 8; ++y) {
        float a1[4], a2[4];
        #pragma unroll
        for (int p = 0; p < 4; ++p) { a1[p] = b1r[p]; a2[p] = b2r[p]; }
        #pragma unroll
        for (int dy = 0; dy < 3; ++dy)
            #pragma unroll
            for (int dx = 0; dx < 3; ++dx) {
                ushort8 v = *reinterpret_cast<const ushort8*>(&T[((y+dy)*34 + xc+dx)*64 + o*8]);
                const int j = dy*3 + dx;
                #pragma unroll
                for (int p = 0; p < 4; ++p) {
                    a1[p] = fmaf(b2f(v[2*p]),   w1r[p][j], a1[p]);
                    a2[p] = fmaf(b2f(v[2*p+1]), w2r[p][j], a2[p]);
                }
            }
        ushort4 ov;
        ov.x = f2b(gelu_exact(a1[0]) * a2[0]);
        ov.y = f2b(gelu_exact(a1[1]) * a2[1]);
        ov.z = f2b(gelu_exact(a1[2]) * a2[2]);
        ov.w = f2b(gelu_exact(a1[3]) * a2[3]);
        *reinterpret_cast<ushort4*>(g + ((long)(y0+y)*192 + x0+xc)*512 + jb + o*4) = ov;
    }
}

extern "C" void kernel_launch(void* const* d_in, const int* in_sizes, int n_in,
                              void* d_out, int out_size, void* d_ws, size_t ws_size,
                              hipStream_t stream) {
    const float* x           = (const float*)d_in[0];
    const float* qkv_w       = (const float*)d_in[1];
    const float* qkv_bias    = (const float*)d_in[2];
    const float* qkv_dw_w    = (const float*)d_in[3];
    const float* qkv_dw_b    = (const float*)d_in[4];
    const float* attn_out_w  = (const float*)d_in[5];
    const float* attn_out_b  = (const float*)d_in[6];
    const float* temperature = (const float*)d_in[7];
    const float* proj_in_w   = (const float*)d_in[8];
    const float* proj_in_b   = (const float*)d_in[9];
    const float* dw_w        = (const float*)d_in[10];
    const float* dw_b        = (const float*)d_in[11];
    const float* proj_out_w  = (const float*)d_in[12];
    const float* proj_out_b  = (const float*)d_in[13];
    float* out = (float*)d_out;
    char* ws = (char*)d_ws;

    // big slots (per-batch reuse)
    u16* A_   = (u16*)ws;                              // [36864][192]  xt -> x2
    u16* C_   = (u16*)(ws + 14155776);                 // [36864][576]  t1 -> g[n][512]
    u16* vbuf = (u16*)(ws + 14155776 + 42467328);      // [36864][192]  v
    u16* qkT  = (u16*)(ws + 14155776 + 42467328 + 14155776);  // [384][36864] q,k transposed
    u16* E_   = vbuf;                                  // t2half [n][512] reuses vbuf+qkT after attn
    // weights / smalls
    char* wsm = ws + 99090432;
    u16* W1p = (u16*)(wsm);                    // 640*192
    u16* W2p = (u16*)(wsm + 245760);           // 1024*192
    u16* W3p = (u16*)(wsm + 245760 + 393216);  // 192*512
    u16* W2b = (u16*)(wsm + 835584);           // 192*192
    float* b1p = (float*)(wsm + 835584 + 73728);   // 640
    float* b2p = b1p + 640;                        // 1024
    float* S_  = b2p + 1024;
    float* nacc = S_;               // 384
    float* s2s  = S_ + 384;         // 192
    float* s2q  = S_ + 576;         // 192
    float* s2m  = S_ + 768;         // 192
    float* s2r  = S_ + 960;         // 192
    float* araw = S_ + 1152;        // 9216
    float* ssm  = S_ + 10368;       // 9216
    float4* st1 = (float4*)(S_ + 19584);   // 384 float4 -> ends S_+21120
    float* apart = S_ + 21120;      // 72*9216 = 663552 floats (2.65 MB)

    stats_k<<<384, 256, 0, stream>>>(x, st1);
    prep3_k<<<192, 256, 0, stream>>>(proj_out_w, W3p);

    for (int b = 0; b < 2; ++b) {
        const float* xb = x + (long)b * 192 * HW;
        float* outb = out + (long)b * 192 * HW;
        const float4* st1b = st1 + b * 192;

        zero_k<<<2, 256, 0, stream>>>(nacc, 384);
        prep1_k<<<640, 192, 0, stream>>>(qkv_w, qkv_bias, st1b, W1p, b1p);
        tn_k<<<576, 256, 0, stream>>>(xb, A_);

        // G1: t1[n][576] = xt @ W1p^T + b1p
        gemm_k<128,0,false><<<dim3(5,288), 256, 0, stream>>>(
            W1p, 192, 3, A_, 192, 0, b1p, nullptr, C_, 576, 576, nullptr);
        dwconv_k<<<dim3(144,9), 256, 0, stream>>>(C_, qkv_dw_w, qkv_dw_b, vbuf, qkT, nacc);
        attnscore_k<<<dim3(72,4), 256, 0, stream>>>(qkT, apart);
        red_k<<<36, 256, 0, stream>>>(apart, araw);
        softmax_sm_k<<<1, 256, 0, stream>>>(araw, nacc, temperature, ssm);
        w2fold_k<<<144, 256, 0, stream>>>(ssm, attn_out_w, W2b);
        // G2: x2 = W2b @ v + attn_out_b + x   (in-place over xt)
        gemm_k<64,1,false><<<dim3(3,288), 256, 0, stream>>>(
            W2b, 192, 3, vbuf, 192, 0, attn_out_b, A_, A_, 192, 192, nullptr);

        stat2_k<<<288, 192, 0, stream>>>(A_, s2s, s2q);
        fin2_k<<<1, 192, 0, stream>>>(s2s, s2q, s2m, s2r);
        prep2_k<<<1024, 192, 0, stream>>>(proj_in_w, proj_in_b, s2m, s2r, W2p, b2p);

        // GDFN in two m-halves (interleaved y1/y2 pairs); t2half reuses vbuf+qkT region
        gemm_k<128,0,false><<<dim3(4,288), 256, 0, stream>>>(
            W2p, 192, 3, A_, 192, 0, b2p, nullptr, E_, 512, 512, nullptr);
        gate_k<<<dim3(144,8), 256, 0, stream>>>(E_, dw_w, dw_b, C_, 0);
        gemm_k<128,0,false><<<dim3(4,288), 256, 0, stream>>>(
            W2p + (long)512*192, 192, 3, A_, 192, 0, b2p + 512, nullptr, E_, 512, 512, nullptr);
        gate_k<<<dim3(144,8), 256, 0, stream>>>(E_, dw_w, dw_b, C_, 256);

        // G4: out = x2 + g @ W3p^T + proj_out_b  (transposed f32 write)
        gemm_k<64,2,true><<<dim3(3,288), 256, 0, stream>>>(
            W3p, 512, 8, C_, 512, 0, proj_out_b, A_, nullptr, 0, 192, outb);
    }
}